// Round 7
// baseline (765.185 us; speedup 1.0000x reference)
//
#include <hip/hip_runtime.h>

typedef unsigned short u16;
typedef unsigned int   u32;
typedef unsigned long long u64;
typedef float f2 __attribute__((ext_vector_type(2)));

#define CIN  20
#define DIN  32
#define BB   4
#define HH   384
#define WW   384
#define HW   147456
#define BHW  589824
#define EPSF 1e-5f
#define GUARD  65536      // streams with <=49152B 4-step overrun
#define UGUARD 131072     // u stream: 4-step overrun 98304 < 128K

__device__ __forceinline__ float bflo(u32 u) {
    union { u32 v; float f; } x; x.v = u << 16; return x.f;
}
__device__ __forceinline__ float bfhi(u32 u) {
    union { u32 v; float f; } x; x.v = u & 0xffff0000u; return x.f;
}
__device__ __forceinline__ float bf2f(u16 h) {
    union { u32 v; float f; } x; x.v = ((u32)h) << 16; return x.f;
}
__device__ __forceinline__ u16 f2bf(float f) {
    union { float f; u32 u; } v; v.f = f;
    u32 u = v.u;
    return (u16)((u + 0x7FFFu + ((u >> 16) & 1u)) >> 16);
}
__device__ __forceinline__ float silu_f(float a) {
    return a / (1.f + __expf(-a));
}
__device__ __forceinline__ float softplus_f(float z) {
    return (z > 15.f) ? z : __logf(1.f + __expf(z));
}

// ---------------- K0: fold merge+out weights ----------------
__global__ void k_prep(const float* __restrict__ ow, const float* __restrict__ mw,
                       const float* __restrict__ mg, const float* __restrict__ mb,
                       const float* __restrict__ ob,
                       float* __restrict__ Wt, float* __restrict__ rsum,
                       float* __restrict__ c0)
{
    __shared__ float mdot[DIN];
    int t = threadIdx.x; // 128 threads
    if (t < DIN) {
        float s = 0.f;
        for (int k = 0; k < 128; ++k) s += mw[t*128 + k] * mb[k];
        mdot[t] = s;
    }
    {
        int k = t;
        for (int o = 0; o < CIN; ++o) {
            float s = 0.f;
            for (int d = 0; d < DIN; ++d) s += ow[o*DIN + d] * mw[d*128 + k];
            Wt[k*CIN + o] = s * mg[k];
        }
    }
    __syncthreads();
    if (t < CIN) {
        float rs = 0.f;
        for (int k = 0; k < 128; ++k) rs += Wt[k*CIN + t];
        rsum[t] = rs;
        float c = ob[t];
        for (int d = 0; d < DIN; ++d) c += ow[t*DIN + d] * mdot[d];
        c0[t] = c;
    }
}

// ---------------- K_FRONT: fused layernorm+inproj+silu -> 3x3 dwconv+silu -> proj ----------------
// 16x16 pixel tile + 1-halo per 256-thread block (384/16 = 24 tiles/dim exact).
// Phase 1: LN+inproj+silu for 18x18 halo pixels -> LDS f32 tile (stride 36 to
//          de-conflict banks). Out-of-image halo = 0 (matches 'SAME' zero pad).
// Phase 2: conv from LDS (f32, no unpack), silu -> u[32] in registers (f32,
//          more accurate than old bf16 round trip), write h2 (bf16 for scan),
//          then 4-dir projection on register u -> dl + bc.
// Removes h1 entirely, h2 re-read, 2 launches, and all interface pack/unpack.
#define TS   16
#define HT   18
#define CPAD 36
__global__ __launch_bounds__(256) void k_front(
    const float* __restrict__ x, const float* __restrict__ ng,
    const float* __restrict__ nb, const float* __restrict__ ipw,
    const float* __restrict__ cw, const float* __restrict__ cb,
    const float* __restrict__ xw,
    u16* __restrict__ h2, u16* __restrict__ dlA, u16* __restrict__ bcA)
{
    __shared__ __align__(16) float hs[HT*HT*CPAD];      // 46656 B
    __shared__ __align__(16) f2 wln_s[CIN*16];          // 2560 B
    __shared__ float g_s[CIN], b_s[CIN];
    __shared__ __align__(16) f2 wc_s[9*16];             // 1152 B
    __shared__ __align__(16) f2 bc2_s[16];
    __shared__ __align__(16) f2 xw2_s[4*DIN*10];        // 10240 B

    int tid = threadIdx.x;
    // ---- weight preload ----
    for (int i = tid; i < CIN*16; i += 256) {
        int c = i >> 4, j2 = i & 15;
        wln_s[i] = f2{ ipw[(2*j2)*CIN + c], ipw[(2*j2+1)*CIN + c] };
    }
    if (tid < CIN) { g_s[tid] = ng[tid]; b_s[tid] = nb[tid]; }
    if (tid < 144) wc_s[tid] = f2{ cw[2*tid], cw[2*tid+1] };
    if (tid >= 144 && tid < 160) {
        int i = tid - 144;
        bc2_s[i] = f2{ cb[2*i], cb[2*i+1] };
    }
    for (int i = tid; i < 4*DIN*10; i += 256) {
        int dir = i / 320, r = i % 320;
        int d = r / 10, j2 = r % 10;
        xw2_s[i] = f2{ xw[(dir*CIN + 2*j2)*DIN + d],
                       xw[(dir*CIN + 2*j2 + 1)*DIN + d] };
    }
    __syncthreads();

    int bx = blockIdx.x;
    int b  = bx / 576, t6 = bx % 576;
    int ty0 = (t6 / 24)*TS, tx0 = (t6 % 24)*TS;

    // ---- phase 1: halo LN+inproj+silu -> LDS ----
    for (int j = tid; j < HT*HT; j += 256) {
        int hy = j / HT, hx = j % HT;
        int gy = ty0 + hy - 1, gx = tx0 + hx - 1;
        float* hp = &hs[(hy*HT + hx)*CPAD];
        if (gy >= 0 && gy < HH && gx >= 0 && gx < WW) {
            int rem = gy*WW + gx;
            float v[CIN];
            float m = 0.f;
            #pragma unroll
            for (int c = 0; c < CIN; ++c) { v[c] = x[(b*CIN + c)*HW + rem]; m += v[c]; }
            m *= (1.f/CIN);
            float var = 0.f;
            #pragma unroll
            for (int c = 0; c < CIN; ++c) { float d = v[c]-m; var += d*d; }
            var *= (1.f/CIN);
            float rstd = rsqrtf(var + EPSF);
            #pragma unroll
            for (int c = 0; c < CIN; ++c) v[c] = (v[c]-m)*rstd*g_s[c] + b_s[c];

            f2 o2[16];
            #pragma unroll
            for (int j2 = 0; j2 < 16; ++j2) o2[j2] = f2{0.f, 0.f};
            #pragma unroll
            for (int c = 0; c < CIN; ++c) {
                f2 vc = { v[c], v[c] };
                const float4* wr = (const float4*)&wln_s[c*16];
                #pragma unroll
                for (int jq = 0; jq < 8; ++jq) {
                    float4 wp = wr[jq];
                    o2[2*jq]   = __builtin_elementwise_fma(f2{wp.x, wp.y}, vc, o2[2*jq]);
                    o2[2*jq+1] = __builtin_elementwise_fma(f2{wp.z, wp.w}, vc, o2[2*jq+1]);
                }
            }
            #pragma unroll
            for (int q = 0; q < 8; ++q) {
                float a0 = silu_f(o2[2*q].x),   a1 = silu_f(o2[2*q].y);
                float a2 = silu_f(o2[2*q+1].x), a3 = silu_f(o2[2*q+1].y);
                *(float4*)&hp[4*q] = make_float4(a0, a1, a2, a3);
            }
        } else {
            #pragma unroll
            for (int q = 0; q < 8; ++q)
                *(float4*)&hp[4*q] = make_float4(0.f, 0.f, 0.f, 0.f);
        }
    }
    __syncthreads();

    // ---- phase 2: conv + silu + proj for the 16x16 interior ----
    int ty = tid >> 4, tx = tid & 15;
    int gy = ty0 + ty, gx = tx0 + tx;
    int p  = b*HW + gy*WW + gx;

    f2 acc2[16];
    #pragma unroll
    for (int i = 0; i < 16; ++i) acc2[i] = bc2_s[i];

    #pragma unroll
    for (int k = 0; k < 9; ++k) {
        int dy = k/3, dx = k%3;     // hs coords: interior pixel = (ty+1, tx+1); tap = (ty+dy, tx+dx)
        const float* np = &hs[((ty+dy)*HT + (tx+dx))*CPAD];
        const f2* wk = &wc_s[k*16];
        #pragma unroll
        for (int q = 0; q < 8; ++q) {
            float4 t4 = *(const float4*)&np[4*q];
            acc2[2*q]   = __builtin_elementwise_fma(wk[2*q],   f2{t4.x, t4.y}, acc2[2*q]);
            acc2[2*q+1] = __builtin_elementwise_fma(wk[2*q+1], f2{t4.z, t4.w}, acc2[2*q+1]);
        }
    }

    float u[DIN];
    #pragma unroll
    for (int i = 0; i < 16; ++i) {
        u[2*i]   = silu_f(acc2[i].x);
        u[2*i+1] = silu_f(acc2[i].y);
    }

    // h2 (bf16) for the scan's u stream
    {
        u32 pk[16];
        #pragma unroll
        for (int i = 0; i < 16; ++i)
            pk[i] = (u32)f2bf(u[2*i]) | ((u32)f2bf(u[2*i+1]) << 16);
        uint4* dst = (uint4*)(h2 + (size_t)p*DIN);
        dst[0] = make_uint4(pk[0],pk[1],pk[2],pk[3]);
        dst[1] = make_uint4(pk[4],pk[5],pk[6],pk[7]);
        dst[2] = make_uint4(pk[8],pk[9],pk[10],pk[11]);
        dst[3] = make_uint4(pk[12],pk[13],pk[14],pk[15]);
    }

    // projection: xdbl = xw . u  (accumulation order over d identical to R6 k_proj)
    #pragma unroll 1
    for (int dir = 0; dir < 4; ++dir) {
        f2 xd2[10];
        #pragma unroll
        for (int j2 = 0; j2 < 10; ++j2) xd2[j2] = f2{0.f, 0.f};
        #pragma unroll
        for (int d = 0; d < DIN; ++d) {
            f2 ud = { u[d], u[d] };
            const float4* wr = (const float4*)&xw2_s[(dir*DIN + d)*10];
            #pragma unroll
            for (int jq = 0; jq < 5; ++jq) {
                float4 wp = wr[jq];
                xd2[2*jq]   = __builtin_elementwise_fma(f2{wp.x, wp.y}, ud, xd2[2*jq]);
                xd2[2*jq+1] = __builtin_elementwise_fma(f2{wp.z, wp.w}, ud, xd2[2*jq+1]);
            }
        }
        u32 pk[10];
        #pragma unroll
        for (int i = 0; i < 10; ++i)
            pk[i] = (u32)f2bf(xd2[i].x) | ((u32)f2bf(xd2[i].y) << 16);
        *(uint2*)(dlA + (size_t)(dir*BHW + p)*4) = make_uint2(pk[0], pk[1]);
        uint4* bcd = (uint4*)(bcA + (size_t)(dir*BHW + p)*16);
        bcd[0] = make_uint4(pk[2], pk[3], pk[4], pk[5]);   // B0..B7
        bcd[1] = make_uint4(pk[6], pk[7], pk[8], pk[9]);   // C0..C7
    }
}

// ---------------- K4: 4-direction selective scan [R2/R6 champion, unchanged] ----------------
// lane = d (32 ch), 2 sequences per wave, 8 states/lane as 4x float2.
// Software-pipelined (prep for t+1 overlaps FMA work of t), prefetch depth 4,
// rcp and log computed in parallel from w = 1+e^z.
__global__ __launch_bounds__(256) void k_scan(
    const char* __restrict__ h2b,   // u data at +UGUARD
    const char* __restrict__ dlb_,  // dl data at +GUARD (8B records)
    const char* __restrict__ bcb_,  // (B,C) data at +GUARD (32B records)
    const float* __restrict__ Alog, const float* __restrict__ Dp,
    const float* __restrict__ dwm,  const float* __restrict__ dbv,
    char* __restrict__ y4b)         // planar (dir, pixel, 32) bf16
{
    int tid  = blockIdx.x*256 + threadIdx.x;
    int wv   = tid >> 6, lane = tid & 63;
    int half = lane >> 5, d = lane & 31;
    int dir  = wv / 768;                 // uniform per wave
    int s    = (wv % 768)*2 + half;
    int b    = s / 384, r = s % 384;

    int p0, stp;
    if (dir == 0)      { p0 = b*HW + r*WW;           stp = 1;  }
    else if (dir == 1) { p0 = b*HW + r*WW + (WW-1);  stp = -1; }
    else if (dir == 2) { p0 = b*HW + r;              stp = WW; }
    else               { p0 = b*HW + (HH-1)*WW + r;  stp = -WW;}

    float Av[8];
    bool okl = true;
    #pragma unroll
    for (int j = 0; j < 8; ++j) {
        float e = __expf(Alog[(dir*DIN + d)*8 + j]);
        Av[j] = -e;
        okl = okl && (__builtin_fabsf(e - (float)(j+1)) < 2e-3f);
    }
    bool fast = (__ballot(okl) == ~0ull);

    float Dd  = Dp[dir*DIN + d];
    float dw0 = dwm[(dir*DIN + d)*4 + 0], dw1 = dwm[(dir*DIN + d)*4 + 1];
    float dw2 = dwm[(dir*DIN + d)*4 + 2], dw3 = dwm[(dir*DIN + d)*4 + 3];
    float dbc = dbv[dir*DIN + d];

    u32 uo = UGUARD + (u32)((p0*DIN + d)*2);           int su = stp*DIN*2;
    u32 yo = (u32)((dir*BHW + p0)*64 + d*2);           int sy = stp*64;
    u32 c1 = GUARD + (u32)((dir*BHW + p0)*8);          int s1 = stp*8;
    u32 c2 = GUARD + (u32)((dir*BHW + p0)*32);         int s2 = stp*32;

    u16 ub[4]; uint2 dlr[4]; uint4 B4[4], C4[4];
    u32 fu = uo, f1 = c1, f2o = c2;

    auto fetch = [&](int sl) {
        ub[sl]  = *(const u16*)(h2b + fu);
        dlr[sl] = *(const uint2*)(dlb_ + f1);
        B4[sl]  = *(const uint4*)(bcb_ + f2o);
        C4[sl]  = *(const uint4*)(bcb_ + f2o + 16);
        fu += (u32)su; f1 += (u32)s1; f2o += (u32)s2;
    };

    #pragma unroll
    for (int i = 0; i < 4; ++i) fetch(i);

    f2 h0 = {0.f,0.f}, h1v = {0.f,0.f}, h2v = {0.f,0.f}, h3 = {0.f,0.f};

    if (fast) {
        f2 a01, a23, a45, a67;
        f2 Bq0, Bq1, Bq2, Bq3;
        f2 Cp0, Cp1, Cp2, Cp3;
        float ydc;

        auto prep = [&](int sl) {
            float uu = bf2f(ub[sl]);
            uint2 dl = dlr[sl];
            uint4 Bv = B4[sl], Cv = C4[sl];
            float z = dbc + dw0*bflo(dl.x) + dw1*bfhi(dl.x)
                          + dw2*bflo(dl.y) + dw3*bfhi(dl.y);
            z = fminf(z, 80.f);
            float ez = __expf(z);
            float w  = 1.f + ez;
            float rr = __builtin_amdgcn_rcpf(w);   // = exp(-dt)
            float dt = __logf(w);                  // softplus(z); parallel with rcp
            float r2 = rr*rr;
            f2 rr2 = {r2, r2};
            f2 t01 = {rr, r2};
            a01 = t01;
            a23 = t01*rr2;
            a45 = a23*rr2;
            a67 = a45*rr2;
            float dtu = dt*uu;
            f2 du2 = {dtu, dtu};
            f2 Bp0 = { bflo(Bv.x), bfhi(Bv.x) }, Bp1 = { bflo(Bv.y), bfhi(Bv.y) };
            f2 Bp2 = { bflo(Bv.z), bfhi(Bv.z) }, Bp3 = { bflo(Bv.w), bfhi(Bv.w) };
            Bq0 = du2*Bp0; Bq1 = du2*Bp1; Bq2 = du2*Bp2; Bq3 = du2*Bp3;
            f2 c0 = { bflo(Cv.x), bfhi(Cv.x) }, c1v = { bflo(Cv.y), bfhi(Cv.y) };
            f2 c2v = { bflo(Cv.z), bfhi(Cv.z) }, c3 = { bflo(Cv.w), bfhi(Cv.w) };
            Cp0 = c0; Cp1 = c1v; Cp2 = c2v; Cp3 = c3;
            ydc = Dd*uu;
        };

        prep(0);

        #pragma unroll 4
        for (int t = 0; t < 384; ++t) {
            int sl = t & 3;
            fetch(sl);

            h0  = __builtin_elementwise_fma(a01, h0,  Bq0);
            h1v = __builtin_elementwise_fma(a23, h1v, Bq1);
            h2v = __builtin_elementwise_fma(a45, h2v, Bq2);
            h3  = __builtin_elementwise_fma(a67, h3,  Bq3);

            f2 yv = Cp0*h0;
            yv = __builtin_elementwise_fma(Cp1, h1v, yv);
            yv = __builtin_elementwise_fma(Cp2, h2v, yv);
            yv = __builtin_elementwise_fma(Cp3, h3,  yv);
            float y = yv.x + yv.y + ydc;

            prep((t+1) & 3);

            *(u16*)(y4b + yo) = f2bf(y);
            yo += (u32)sy;
        }
    } else {
        f2 A2[4];
        #pragma unroll
        for (int j = 0; j < 4; ++j) { A2[j].x = Av[2*j]; A2[j].y = Av[2*j+1]; }
        #pragma unroll 4
        for (int t = 0; t < 384; ++t) {
            int sl = t & 3;
            float uu = bf2f(ub[sl]);
            uint2 dl = dlr[sl];
            uint4 Bv = B4[sl], Cv = C4[sl];
            fetch(sl);

            float z = dbc + dw0*bflo(dl.x) + dw1*bfhi(dl.x)
                          + dw2*bflo(dl.y) + dw3*bfhi(dl.y);
            float dt = softplus_f(z);
            f2 dt2 = {dt, dt};
            f2 e0 = dt2*A2[0], e1 = dt2*A2[1], e2 = dt2*A2[2], e3 = dt2*A2[3];
            f2 a01 = { __expf(e0.x), __expf(e0.y) };
            f2 a23 = { __expf(e1.x), __expf(e1.y) };
            f2 a45 = { __expf(e2.x), __expf(e2.y) };
            f2 a67 = { __expf(e3.x), __expf(e3.y) };

            float dtu = dt*uu;
            f2 du2 = {dtu, dtu};
            f2 Bp0 = { bflo(Bv.x), bfhi(Bv.x) }, Bp1 = { bflo(Bv.y), bfhi(Bv.y) };
            f2 Bp2 = { bflo(Bv.z), bfhi(Bv.z) }, Bp3 = { bflo(Bv.w), bfhi(Bv.w) };
            f2 Cp0 = { bflo(Cv.x), bfhi(Cv.x) }, Cp1 = { bflo(Cv.y), bfhi(Cv.y) };
            f2 Cp2 = { bflo(Cv.z), bfhi(Cv.z) }, Cp3 = { bflo(Cv.w), bfhi(Cv.w) };

            h0  = __builtin_elementwise_fma(a01, h0,  du2*Bp0);
            h1v = __builtin_elementwise_fma(a23, h1v, du2*Bp1);
            h2v = __builtin_elementwise_fma(a45, h2v, du2*Bp2);
            h3  = __builtin_elementwise_fma(a67, h3,  du2*Bp3);

            f2 yv = Cp0*h0;
            yv = __builtin_elementwise_fma(Cp1, h1v, yv);
            yv = __builtin_elementwise_fma(Cp2, h2v, yv);
            yv = __builtin_elementwise_fma(Cp3, h3,  yv);

            float y = yv.x + yv.y + Dd*uu;
            *(u16*)(y4b + yo) = f2bf(y);
            yo += (u32)sy;
        }
    }
}

// ---------------- K5: LN(128) + folded 128->20 + NCHW transpose (pk-FMA, R6) ----------------
__global__ __launch_bounds__(256) void k_merge(
    const u16* __restrict__ y4, const float* __restrict__ Wt,
    const float* __restrict__ rsum, const float* __restrict__ c0,
    float* __restrict__ out)
{
    __shared__ __align__(16) f2 Wt2_s[128*10];   // [k][o2] = {Wt[k][2o2], Wt[k][2o2+1]}
    __shared__ float rs_s[CIN], c0_s[CIN];
    for (int i = threadIdx.x; i < 128*10; i += 256) {
        int k = i / 10, o2 = i % 10;
        Wt2_s[i] = f2{ Wt[k*CIN + 2*o2], Wt[k*CIN + 2*o2 + 1] };
    }
    if (threadIdx.x < CIN) { rs_s[threadIdx.x] = rsum[threadIdx.x]; c0_s[threadIdx.x] = c0[threadIdx.x]; }
    __syncthreads();

    int p = blockIdx.x*256 + threadIdx.x;
    int b = p / HW, rem = p % HW;

    float s1 = 0.f, s2 = 0.f;
    f2 acc2[10];
    #pragma unroll
    for (int o2 = 0; o2 < 10; ++o2) acc2[o2] = f2{0.f, 0.f};

    #pragma unroll 1
    for (int dirk = 0; dirk < 4; ++dirk) {
        const uint4* src = (const uint4*)(y4 + ((size_t)dirk*BHW + p)*32);
        #pragma unroll
        for (int q4 = 0; q4 < 4; ++q4) {
            uint4 v = src[q4];
            u32 w[4] = {v.x, v.y, v.z, v.w};
            #pragma unroll
            for (int i = 0; i < 4; ++i) {
                int k = dirk*32 + q4*8 + i*2;
                float a = bflo(w[i]); float c = bfhi(w[i]);
                s1 += a + c; s2 += a*a + c*c;
                f2 af = {a, a}, cf = {c, c};
                const float4* w0 = (const float4*)&Wt2_s[k*10];
                const float4* w1 = (const float4*)&Wt2_s[(k+1)*10];
                #pragma unroll
                for (int jq = 0; jq < 5; ++jq) {
                    float4 x0 = w0[jq], x1 = w1[jq];
                    acc2[2*jq]   = __builtin_elementwise_fma(f2{x0.x, x0.y}, af, acc2[2*jq]);
                    acc2[2*jq]   = __builtin_elementwise_fma(f2{x1.x, x1.y}, cf, acc2[2*jq]);
                    acc2[2*jq+1] = __builtin_elementwise_fma(f2{x0.z, x0.w}, af, acc2[2*jq+1]);
                    acc2[2*jq+1] = __builtin_elementwise_fma(f2{x1.z, x1.w}, cf, acc2[2*jq+1]);
                }
            }
        }
    }
    float m = s1*(1.f/128.f);
    float var = s2*(1.f/128.f) - m*m;
    float rstd = rsqrtf(var + EPSF);
    #pragma unroll
    for (int o2 = 0; o2 < 10; ++o2) {
        float r0 = rstd*(acc2[o2].x - m*rs_s[2*o2])   + c0_s[2*o2];
        float r1 = rstd*(acc2[o2].y - m*rs_s[2*o2+1]) + c0_s[2*o2+1];
        out[(b*CIN + 2*o2)*HW + rem]   = r0;
        out[(b*CIN + 2*o2+1)*HW + rem] = r1;
    }
}

extern "C" void kernel_launch(void* const* d_in, const int* in_sizes, int n_in,
                              void* d_out, int out_size, void* d_ws, size_t ws_size,
                              hipStream_t stream)
{
    const float* x    = (const float*)d_in[0];
    const float* ng   = (const float*)d_in[1];
    const float* nb   = (const float*)d_in[2];
    const float* ipw  = (const float*)d_in[3];
    const float* cw   = (const float*)d_in[4];
    const float* cb   = (const float*)d_in[5];
    const float* xw   = (const float*)d_in[6];
    const float* dwm  = (const float*)d_in[7];
    const float* dbv  = (const float*)d_in[8];
    const float* Alog = (const float*)d_in[9];
    const float* Dpv  = (const float*)d_in[10];
    const float* mg   = (const float*)d_in[11];
    const float* mb   = (const float*)d_in[12];
    const float* mw   = (const float*)d_in[13];
    const float* ow   = (const float*)d_in[14];
    const float* ob   = (const float*)d_in[15];
    float* out = (float*)d_out;

    const size_t y4_bytes = (size_t)4*BHW*DIN*2;     // 150,994,944 (planar)
    const size_t dl_bytes = (size_t)4*BHW*8;         //  18,874,368
    const size_t bc_bytes = (size_t)4*BHW*32;        //  75,497,472
    const size_t wt_bytes = (size_t)(128*CIN + 64)*4;

    char* ws = (char*)d_ws;
    u16* y4 = (u16*)ws;

    size_t dl_pos = y4_bytes + GUARD;
    size_t bc_pos = dl_pos + dl_bytes + GUARD;
    size_t wt_pos = bc_pos + bc_bytes + GUARD;
    size_t need   = wt_pos + wt_bytes + GUARD;       // ~245.6 MB (proven budget; ws < 321MB per R4)

    if (ws_size < need) {
        hipMemsetAsync(d_out, 0x7F, (size_t)out_size*4, stream);  // diagnosable sentinel
        return;
    }

    // h2 (u after conv) lives inside d_out with UGUARD front guard (128K for
    // 4-deep prefetch overrun of the vertical-scan u stream: 4*24576 = 96K).
    char* h2base = (char*)d_out;                     // data at +UGUARD
    u16*  h2 = (u16*)(h2base + UGUARD);              // 128K + 37.75MB + 9.3MB tail < 47.19 MB

    u16* dlA = (u16*)(ws + dl_pos);
    u16* bcA = (u16*)(ws + bc_pos);
    float* Wt   = (float*)(ws + wt_pos);
    float* rsum = Wt + 128*CIN;
    float* c0   = rsum + 32;

    k_prep  <<<1, 128, 0, stream>>>(ow, mw, mg, mb, ob, Wt, rsum, c0);
    k_front <<<2304, 256, 0, stream>>>(x, ng, nb, ipw, cw, cb, xw, h2, dlA, bcA);
    k_scan  <<<768, 256, 0, stream>>>(
        h2base, (const char*)(ws + dl_pos - GUARD), (const char*)(ws + bc_pos - GUARD),
        Alog, Dpv, dwm, dbv, (char*)y4);
    k_merge <<<BHW/256, 256, 0, stream>>>(y4, Wt, rsum, c0, out);
}

// Round 9
// 760.254 us; speedup vs baseline: 1.0065x; 1.0065x over previous
//
#include <hip/hip_runtime.h>

typedef unsigned short u16;
typedef unsigned int   u32;
typedef unsigned long long u64;
typedef float f2 __attribute__((ext_vector_type(2)));

#define CIN  20
#define DIN  32
#define BB   4
#define HH   384
#define WW   384
#define HW   147456
#define BHW  589824
#define EPSF 1e-5f
#define GUARD  65536      // streams with <=49152B 4-step overrun
#define UGUARD 131072     // u stream: 4-step overrun 98304 < 128K

__device__ __forceinline__ float bflo(u32 u) {
    union { u32 v; float f; } x; x.v = u << 16; return x.f;
}
__device__ __forceinline__ float bfhi(u32 u) {
    union { u32 v; float f; } x; x.v = u & 0xffff0000u; return x.f;
}
__device__ __forceinline__ float bf2f(u16 h) {
    union { u32 v; float f; } x; x.v = ((u32)h) << 16; return x.f;
}
__device__ __forceinline__ u16 f2bf(float f) {
    union { float f; u32 u; } v; v.f = f;
    u32 u = v.u;
    return (u16)((u + 0x7FFFu + ((u >> 16) & 1u)) >> 16);
}
__device__ __forceinline__ float silu_f(float a) {
    return a / (1.f + __expf(-a));
}
__device__ __forceinline__ float softplus_f(float z) {
    return (z > 15.f) ? z : __logf(1.f + __expf(z));
}

// ---------------- K0: fold merge+out weights ----------------
__global__ void k_prep(const float* __restrict__ ow, const float* __restrict__ mw,
                       const float* __restrict__ mg, const float* __restrict__ mb,
                       const float* __restrict__ ob,
                       float* __restrict__ Wt, float* __restrict__ rsum,
                       float* __restrict__ c0)
{
    __shared__ float mdot[DIN];
    int t = threadIdx.x; // 128 threads
    if (t < DIN) {
        float s = 0.f;
        for (int k = 0; k < 128; ++k) s += mw[t*128 + k] * mb[k];
        mdot[t] = s;
    }
    {
        int k = t;
        for (int o = 0; o < CIN; ++o) {
            float s = 0.f;
            for (int d = 0; d < DIN; ++d) s += ow[o*DIN + d] * mw[d*128 + k];
            Wt[k*CIN + o] = s * mg[k];
        }
    }
    __syncthreads();
    if (t < CIN) {
        float rs = 0.f;
        for (int k = 0; k < 128; ++k) rs += Wt[k*CIN + t];
        rsum[t] = rs;
        float c = ob[t];
        for (int d = 0; d < DIN; ++d) c += ow[t*DIN + d] * mdot[d];
        c0[t] = c;
    }
}

// ---------------- K_LNCONV: fused layernorm+inproj+silu -> 3x3 dwconv+silu ----------------
// 16x16 tile + 1-halo (R7's phase 1+2, proj REMOVED to keep VGPR < 128 —
// R7's 256-VGPR spill storm came from carrying the unrolled projection too).
// Phase 1: LN+inproj+silu for 18x18 halo -> LDS f32 tile. Phase 2: conv+silu
// from LDS (f32, no unpacks) -> h2 bf16. Eliminates h1 round trip entirely.
#define TS   16
#define HT   18
#define CPAD 36
__global__ __launch_bounds__(256) void k_lnconv(
    const float* __restrict__ x, const float* __restrict__ ng,
    const float* __restrict__ nb, const float* __restrict__ ipw,
    const float* __restrict__ cw, const float* __restrict__ cb,
    u16* __restrict__ h2)
{
    __shared__ __align__(16) float hs[HT*HT*CPAD];      // 46656 B
    __shared__ __align__(16) f2 wln_s[CIN*16];          // 2560 B
    __shared__ float g_s[CIN], b_s[CIN];
    __shared__ __align__(16) f2 wc_s[9*16];             // 1152 B
    __shared__ __align__(16) f2 bc2_s[16];

    int tid = threadIdx.x;
    for (int i = tid; i < CIN*16; i += 256) {
        int c = i >> 4, j2 = i & 15;
        wln_s[i] = f2{ ipw[(2*j2)*CIN + c], ipw[(2*j2+1)*CIN + c] };
    }
    if (tid < CIN) { g_s[tid] = ng[tid]; b_s[tid] = nb[tid]; }
    if (tid < 144) wc_s[tid] = f2{ cw[2*tid], cw[2*tid+1] };
    if (tid >= 144 && tid < 160) {
        int i = tid - 144;
        bc2_s[i] = f2{ cb[2*i], cb[2*i+1] };
    }
    __syncthreads();

    int bx = blockIdx.x;
    int b  = bx / 576, t6 = bx % 576;
    int ty0 = (t6 / 24)*TS, tx0 = (t6 % 24)*TS;

    // ---- phase 1: halo LN+inproj+silu -> LDS ----
    for (int j = tid; j < HT*HT; j += 256) {
        int hy = j / HT, hx = j % HT;
        int gy = ty0 + hy - 1, gx = tx0 + hx - 1;
        float* hp = &hs[(hy*HT + hx)*CPAD];
        if (gy >= 0 && gy < HH && gx >= 0 && gx < WW) {
            int rem = gy*WW + gx;
            float v[CIN];
            float m = 0.f;
            #pragma unroll
            for (int c = 0; c < CIN; ++c) { v[c] = x[(b*CIN + c)*HW + rem]; m += v[c]; }
            m *= (1.f/CIN);
            float var = 0.f;
            #pragma unroll
            for (int c = 0; c < CIN; ++c) { float d = v[c]-m; var += d*d; }
            var *= (1.f/CIN);
            float rstd = rsqrtf(var + EPSF);
            #pragma unroll
            for (int c = 0; c < CIN; ++c) v[c] = (v[c]-m)*rstd*g_s[c] + b_s[c];

            f2 o2[16];
            #pragma unroll
            for (int j2 = 0; j2 < 16; ++j2) o2[j2] = f2{0.f, 0.f};
            #pragma unroll
            for (int c = 0; c < CIN; ++c) {
                f2 vc = { v[c], v[c] };
                const float4* wr = (const float4*)&wln_s[c*16];
                #pragma unroll
                for (int jq = 0; jq < 8; ++jq) {
                    float4 wp = wr[jq];
                    o2[2*jq]   = __builtin_elementwise_fma(f2{wp.x, wp.y}, vc, o2[2*jq]);
                    o2[2*jq+1] = __builtin_elementwise_fma(f2{wp.z, wp.w}, vc, o2[2*jq+1]);
                }
            }
            #pragma unroll
            for (int q = 0; q < 8; ++q) {
                float a0 = silu_f(o2[2*q].x),   a1 = silu_f(o2[2*q].y);
                float a2 = silu_f(o2[2*q+1].x), a3 = silu_f(o2[2*q+1].y);
                *(float4*)&hp[4*q] = make_float4(a0, a1, a2, a3);
            }
        } else {
            #pragma unroll
            for (int q = 0; q < 8; ++q)
                *(float4*)&hp[4*q] = make_float4(0.f, 0.f, 0.f, 0.f);
        }
    }
    __syncthreads();

    // ---- phase 2: conv + silu -> h2 ----
    int ty = tid >> 4, tx = tid & 15;
    int gy = ty0 + ty, gx = tx0 + tx;
    int p  = b*HW + gy*WW + gx;

    f2 acc2[16];
    #pragma unroll
    for (int i = 0; i < 16; ++i) acc2[i] = bc2_s[i];

    #pragma unroll
    for (int k = 0; k < 9; ++k) {
        int dy = k/3, dx = k%3;
        const float* np = &hs[((ty+dy)*HT + (tx+dx))*CPAD];
        const f2* wk = &wc_s[k*16];
        #pragma unroll
        for (int q = 0; q < 8; ++q) {
            float4 t4 = *(const float4*)&np[4*q];
            acc2[2*q]   = __builtin_elementwise_fma(wk[2*q],   f2{t4.x, t4.y}, acc2[2*q]);
            acc2[2*q+1] = __builtin_elementwise_fma(wk[2*q+1], f2{t4.z, t4.w}, acc2[2*q+1]);
        }
    }

    u32 pk[16];
    #pragma unroll
    for (int i = 0; i < 16; ++i) {
        float a = silu_f(acc2[i].x);
        float c = silu_f(acc2[i].y);
        pk[i] = (u32)f2bf(a) | ((u32)f2bf(c) << 16);
    }
    uint4* dst = (uint4*)(h2 + (size_t)p*DIN);
    dst[0] = make_uint4(pk[0],pk[1],pk[2],pk[3]);
    dst[1] = make_uint4(pk[4],pk[5],pk[6],pk[7]);
    dst[2] = make_uint4(pk[8],pk[9],pk[10],pk[11]);
    dst[3] = make_uint4(pk[12],pk[13],pk[14],pk[15]);
}

// ---------------- K3: xdbl -> dl + BC, pk-FMA, 2-pixel register blocking ----------------
// Each thread handles pixels (p, p+1): wave-uniform weight ds_reads amortize
// 2x (640 -> 320 per pixel); pair stores merge into full uint4s.
// Per-pixel accumulation order identical to R6 (bit-exact).
__global__ __launch_bounds__(256) void k_proj(
    const u16* __restrict__ h2, const float* __restrict__ xw,
    u16* __restrict__ dlA, u16* __restrict__ bcA)
{
    __shared__ __align__(16) f2 xw2_s[4*DIN*10];
    for (int i = threadIdx.x; i < 4*DIN*10; i += 256) {
        int dir = i / 320, r = i % 320;
        int d = r / 10, j2 = r % 10;
        xw2_s[i] = f2{ xw[(dir*CIN + 2*j2)*DIN + d],
                       xw[(dir*CIN + 2*j2 + 1)*DIN + d] };
    }
    __syncthreads();

    int p = (blockIdx.x*256 + threadIdx.x)*2;
    float ua[DIN], ub[DIN];
    const uint4* src = (const uint4*)(h2 + (size_t)p*DIN);
    #pragma unroll
    for (int q4 = 0; q4 < 4; ++q4) {
        uint4 v = src[q4];
        ua[q4*8+0]=bflo(v.x); ua[q4*8+1]=bfhi(v.x);
        ua[q4*8+2]=bflo(v.y); ua[q4*8+3]=bfhi(v.y);
        ua[q4*8+4]=bflo(v.z); ua[q4*8+5]=bfhi(v.z);
        ua[q4*8+6]=bflo(v.w); ua[q4*8+7]=bfhi(v.w);
        uint4 w = src[q4+4];
        ub[q4*8+0]=bflo(w.x); ub[q4*8+1]=bfhi(w.x);
        ub[q4*8+2]=bflo(w.y); ub[q4*8+3]=bfhi(w.y);
        ub[q4*8+4]=bflo(w.z); ub[q4*8+5]=bfhi(w.z);
        ub[q4*8+6]=bflo(w.w); ub[q4*8+7]=bfhi(w.w);
    }
    #pragma unroll 1
    for (int dir = 0; dir < 4; ++dir) {
        f2 xa[10], xb[10];
        #pragma unroll
        for (int j2 = 0; j2 < 10; ++j2) { xa[j2] = f2{0.f,0.f}; xb[j2] = f2{0.f,0.f}; }
        #pragma unroll
        for (int d = 0; d < DIN; ++d) {
            f2 uda = { ua[d], ua[d] };
            f2 udb = { ub[d], ub[d] };
            const float4* wr = (const float4*)&xw2_s[(dir*DIN + d)*10];
            #pragma unroll
            for (int jq = 0; jq < 5; ++jq) {
                float4 wp = wr[jq];
                f2 wlo = {wp.x, wp.y}, whi = {wp.z, wp.w};
                xa[2*jq]   = __builtin_elementwise_fma(wlo, uda, xa[2*jq]);
                xa[2*jq+1] = __builtin_elementwise_fma(whi, uda, xa[2*jq+1]);
                xb[2*jq]   = __builtin_elementwise_fma(wlo, udb, xb[2*jq]);
                xb[2*jq+1] = __builtin_elementwise_fma(whi, udb, xb[2*jq+1]);
            }
        }
        u32 pa[10], pb[10];
        #pragma unroll
        for (int i = 0; i < 10; ++i) {
            pa[i] = (u32)f2bf(xa[i].x) | ((u32)f2bf(xa[i].y) << 16);
            pb[i] = (u32)f2bf(xb[i].x) | ((u32)f2bf(xb[i].y) << 16);
        }
        // dl: two adjacent 8B records -> one uint4 (16B aligned: p even)
        *(uint4*)(dlA + (size_t)(dir*BHW + p)*4) = make_uint4(pa[0], pa[1], pb[0], pb[1]);
        // bc: two adjacent 32B records -> four uint4
        uint4* bcd = (uint4*)(bcA + (size_t)(dir*BHW + p)*16);
        bcd[0] = make_uint4(pa[2], pa[3], pa[4], pa[5]);   // A: B0..B7
        bcd[1] = make_uint4(pa[6], pa[7], pa[8], pa[9]);   // A: C0..C7
        bcd[2] = make_uint4(pb[2], pb[3], pb[4], pb[5]);   // B: B0..B7
        bcd[3] = make_uint4(pb[6], pb[7], pb[8], pb[9]);   // B: C0..C7
    }
}

// ---------------- K4: 4-direction selective scan [R2/R6 champion, unchanged] ----------------
__global__ __launch_bounds__(256) void k_scan(
    const char* __restrict__ h2b,   // u data at +UGUARD
    const char* __restrict__ dlb_,  // dl data at +GUARD (8B records)
    const char* __restrict__ bcb_,  // (B,C) data at +GUARD (32B records)
    const float* __restrict__ Alog, const float* __restrict__ Dp,
    const float* __restrict__ dwm,  const float* __restrict__ dbv,
    char* __restrict__ y4b)         // planar (dir, pixel, 32) bf16
{
    int tid  = blockIdx.x*256 + threadIdx.x;
    int wv   = tid >> 6, lane = tid & 63;
    int half = lane >> 5, d = lane & 31;
    int dir  = wv / 768;                 // uniform per wave
    int s    = (wv % 768)*2 + half;
    int b    = s / 384, r = s % 384;

    int p0, stp;
    if (dir == 0)      { p0 = b*HW + r*WW;           stp = 1;  }
    else if (dir == 1) { p0 = b*HW + r*WW + (WW-1);  stp = -1; }
    else if (dir == 2) { p0 = b*HW + r;              stp = WW; }
    else               { p0 = b*HW + (HH-1)*WW + r;  stp = -WW;}

    float Av[8];
    bool okl = true;
    #pragma unroll
    for (int j = 0; j < 8; ++j) {
        float e = __expf(Alog[(dir*DIN + d)*8 + j]);
        Av[j] = -e;
        okl = okl && (__builtin_fabsf(e - (float)(j+1)) < 2e-3f);
    }
    bool fast = (__ballot(okl) == ~0ull);

    float Dd  = Dp[dir*DIN + d];
    float dw0 = dwm[(dir*DIN + d)*4 + 0], dw1 = dwm[(dir*DIN + d)*4 + 1];
    float dw2 = dwm[(dir*DIN + d)*4 + 2], dw3 = dwm[(dir*DIN + d)*4 + 3];
    float dbc = dbv[dir*DIN + d];

    u32 uo = UGUARD + (u32)((p0*DIN + d)*2);           int su = stp*DIN*2;
    u32 yo = (u32)((dir*BHW + p0)*64 + d*2);           int sy = stp*64;
    u32 c1 = GUARD + (u32)((dir*BHW + p0)*8);          int s1 = stp*8;
    u32 c2 = GUARD + (u32)((dir*BHW + p0)*32);         int s2 = stp*32;

    u16 ub[4]; uint2 dlr[4]; uint4 B4[4], C4[4];
    u32 fu = uo, f1 = c1, f2o = c2;

    auto fetch = [&](int sl) {
        ub[sl]  = *(const u16*)(h2b + fu);
        dlr[sl] = *(const uint2*)(dlb_ + f1);
        B4[sl]  = *(const uint4*)(bcb_ + f2o);
        C4[sl]  = *(const uint4*)(bcb_ + f2o + 16);
        fu += (u32)su; f1 += (u32)s1; f2o += (u32)s2;
    };

    #pragma unroll
    for (int i = 0; i < 4; ++i) fetch(i);

    f2 h0 = {0.f,0.f}, h1v = {0.f,0.f}, h2v = {0.f,0.f}, h3 = {0.f,0.f};

    if (fast) {
        f2 a01, a23, a45, a67;
        f2 Bq0, Bq1, Bq2, Bq3;
        f2 Cp0, Cp1, Cp2, Cp3;
        float ydc;

        auto prep = [&](int sl) {
            float uu = bf2f(ub[sl]);
            uint2 dl = dlr[sl];
            uint4 Bv = B4[sl], Cv = C4[sl];
            float z = dbc + dw0*bflo(dl.x) + dw1*bfhi(dl.x)
                          + dw2*bflo(dl.y) + dw3*bfhi(dl.y);
            z = fminf(z, 80.f);
            float ez = __expf(z);
            float w  = 1.f + ez;
            float rr = __builtin_amdgcn_rcpf(w);   // = exp(-dt)
            float dt = __logf(w);                  // softplus(z); parallel with rcp
            float r2 = rr*rr;
            f2 rr2 = {r2, r2};
            f2 t01 = {rr, r2};
            a01 = t01;
            a23 = t01*rr2;
            a45 = a23*rr2;
            a67 = a45*rr2;
            float dtu = dt*uu;
            f2 du2 = {dtu, dtu};
            f2 Bp0 = { bflo(Bv.x), bfhi(Bv.x) }, Bp1 = { bflo(Bv.y), bfhi(Bv.y) };
            f2 Bp2 = { bflo(Bv.z), bfhi(Bv.z) }, Bp3 = { bflo(Bv.w), bfhi(Bv.w) };
            Bq0 = du2*Bp0; Bq1 = du2*Bp1; Bq2 = du2*Bp2; Bq3 = du2*Bp3;
            f2 c0 = { bflo(Cv.x), bfhi(Cv.x) }, c1v = { bflo(Cv.y), bfhi(Cv.y) };
            f2 c2v = { bflo(Cv.z), bfhi(Cv.z) }, c3 = { bflo(Cv.w), bfhi(Cv.w) };
            Cp0 = c0; Cp1 = c1v; Cp2 = c2v; Cp3 = c3;
            ydc = Dd*uu;
        };

        prep(0);

        #pragma unroll 4
        for (int t = 0; t < 384; ++t) {
            int sl = t & 3;
            fetch(sl);

            h0  = __builtin_elementwise_fma(a01, h0,  Bq0);
            h1v = __builtin_elementwise_fma(a23, h1v, Bq1);
            h2v = __builtin_elementwise_fma(a45, h2v, Bq2);
            h3  = __builtin_elementwise_fma(a67, h3,  Bq3);

            f2 yv = Cp0*h0;
            yv = __builtin_elementwise_fma(Cp1, h1v, yv);
            yv = __builtin_elementwise_fma(Cp2, h2v, yv);
            yv = __builtin_elementwise_fma(Cp3, h3,  yv);
            float y = yv.x + yv.y + ydc;

            prep((t+1) & 3);

            *(u16*)(y4b + yo) = f2bf(y);
            yo += (u32)sy;
        }
    } else {
        f2 A2[4];
        #pragma unroll
        for (int j = 0; j < 4; ++j) { A2[j].x = Av[2*j]; A2[j].y = Av[2*j+1]; }
        #pragma unroll 4
        for (int t = 0; t < 384; ++t) {
            int sl = t & 3;
            float uu = bf2f(ub[sl]);
            uint2 dl = dlr[sl];
            uint4 Bv = B4[sl], Cv = C4[sl];
            fetch(sl);

            float z = dbc + dw0*bflo(dl.x) + dw1*bfhi(dl.x)
                          + dw2*bflo(dl.y) + dw3*bfhi(dl.y);
            float dt = softplus_f(z);
            f2 dt2 = {dt, dt};
            f2 e0 = dt2*A2[0], e1 = dt2*A2[1], e2 = dt2*A2[2], e3 = dt2*A2[3];
            f2 a01 = { __expf(e0.x), __expf(e0.y) };
            f2 a23 = { __expf(e1.x), __expf(e1.y) };
            f2 a45 = { __expf(e2.x), __expf(e2.y) };
            f2 a67 = { __expf(e3.x), __expf(e3.y) };

            float dtu = dt*uu;
            f2 du2 = {dtu, dtu};
            f2 Bp0 = { bflo(Bv.x), bfhi(Bv.x) }, Bp1 = { bflo(Bv.y), bfhi(Bv.y) };
            f2 Bp2 = { bflo(Bv.z), bfhi(Bv.z) }, Bp3 = { bflo(Bv.w), bfhi(Bv.w) };
            f2 Cp0 = { bflo(Cv.x), bfhi(Cv.x) }, Cp1 = { bflo(Cv.y), bfhi(Cv.y) };
            f2 Cp2 = { bflo(Cv.z), bfhi(Cv.z) }, Cp3 = { bflo(Cv.w), bfhi(Cv.w) };

            h0  = __builtin_elementwise_fma(a01, h0,  du2*Bp0);
            h1v = __builtin_elementwise_fma(a23, h1v, du2*Bp1);
            h2v = __builtin_elementwise_fma(a45, h2v, du2*Bp2);
            h3  = __builtin_elementwise_fma(a67, h3,  du2*Bp3);

            f2 yv = Cp0*h0;
            yv = __builtin_elementwise_fma(Cp1, h1v, yv);
            yv = __builtin_elementwise_fma(Cp2, h2v, yv);
            yv = __builtin_elementwise_fma(Cp3, h3,  yv);

            float y = yv.x + yv.y + Dd*uu;
            *(u16*)(y4b + yo) = f2bf(y);
            yo += (u32)sy;
        }
    }
}

// ---------------- K5: LN(128) + folded 128->20 + transpose, 2-pixel blocking ----------------
// Each thread handles pixels (p, p+1): Wt ds_reads amortize 2x; out written
// as float2 (rem even). Per-pixel accumulation order identical to R6.
__global__ __launch_bounds__(256) void k_merge(
    const u16* __restrict__ y4, const float* __restrict__ Wt,
    const float* __restrict__ rsum, const float* __restrict__ c0,
    float* __restrict__ out)
{
    __shared__ __align__(16) f2 Wt2_s[128*10];   // [k][o2] = {Wt[k][2o2], Wt[k][2o2+1]}
    __shared__ float rs_s[CIN], c0_s[CIN];
    for (int i = threadIdx.x; i < 128*10; i += 256) {
        int k = i / 10, o2 = i % 10;
        Wt2_s[i] = f2{ Wt[k*CIN + 2*o2], Wt[k*CIN + 2*o2 + 1] };
    }
    if (threadIdx.x < CIN) { rs_s[threadIdx.x] = rsum[threadIdx.x]; c0_s[threadIdx.x] = c0[threadIdx.x]; }
    __syncthreads();

    int p = (blockIdx.x*256 + threadIdx.x)*2;
    int b = p / HW, rem = p % HW;    // p even, HW even: pair never straddles b

    float s1a = 0.f, s2a = 0.f, s1b = 0.f, s2b = 0.f;
    f2 acca[10], accb[10];
    #pragma unroll
    for (int o2 = 0; o2 < 10; ++o2) { acca[o2] = f2{0.f,0.f}; accb[o2] = f2{0.f,0.f}; }

    #pragma unroll 1
    for (int dirk = 0; dirk < 4; ++dirk) {
        const uint4* src = (const uint4*)(y4 + ((size_t)dirk*BHW + p)*32);
        #pragma unroll
        for (int q4 = 0; q4 < 4; ++q4) {
            uint4 va = src[q4];
            uint4 vb = src[q4+4];
            u32 wa[4] = {va.x, va.y, va.z, va.w};
            u32 wb[4] = {vb.x, vb.y, vb.z, vb.w};
            #pragma unroll
            for (int i = 0; i < 4; ++i) {
                int k = dirk*32 + q4*8 + i*2;
                float aa = bflo(wa[i]); float ca = bfhi(wa[i]);
                float ab = bflo(wb[i]); float cb = bfhi(wb[i]);
                s1a += aa + ca; s2a += aa*aa + ca*ca;
                s1b += ab + cb; s2b += ab*ab + cb*cb;
                f2 afa = {aa, aa}, cfa = {ca, ca};
                f2 afb = {ab, ab}, cfb = {cb, cb};
                const float4* w0 = (const float4*)&Wt2_s[k*10];
                const float4* w1 = (const float4*)&Wt2_s[(k+1)*10];
                #pragma unroll
                for (int jq = 0; jq < 5; ++jq) {
                    float4 x0 = w0[jq], x1 = w1[jq];
                    f2 x0lo = {x0.x, x0.y}, x0hi = {x0.z, x0.w};
                    f2 x1lo = {x1.x, x1.y}, x1hi = {x1.z, x1.w};
                    acca[2*jq]   = __builtin_elementwise_fma(x0lo, afa, acca[2*jq]);
                    acca[2*jq]   = __builtin_elementwise_fma(x1lo, cfa, acca[2*jq]);
                    acca[2*jq+1] = __builtin_elementwise_fma(x0hi, afa, acca[2*jq+1]);
                    acca[2*jq+1] = __builtin_elementwise_fma(x1hi, cfa, acca[2*jq+1]);
                    accb[2*jq]   = __builtin_elementwise_fma(x0lo, afb, accb[2*jq]);
                    accb[2*jq]   = __builtin_elementwise_fma(x1lo, cfb, accb[2*jq]);
                    accb[2*jq+1] = __builtin_elementwise_fma(x0hi, afb, accb[2*jq+1]);
                    accb[2*jq+1] = __builtin_elementwise_fma(x1hi, cfb, accb[2*jq+1]);
                }
            }
        }
    }
    float ma = s1a*(1.f/128.f);
    float va = s2a*(1.f/128.f) - ma*ma;
    float ra = rsqrtf(va + EPSF);
    float mb2 = s1b*(1.f/128.f);
    float vb2 = s2b*(1.f/128.f) - mb2*mb2;
    float rb = rsqrtf(vb2 + EPSF);
    #pragma unroll
    for (int o2 = 0; o2 < 10; ++o2) {
        float a0 = ra*(acca[o2].x - ma*rs_s[2*o2])    + c0_s[2*o2];
        float a1 = ra*(acca[o2].y - ma*rs_s[2*o2+1])  + c0_s[2*o2+1];
        float b0 = rb*(accb[o2].x - mb2*rs_s[2*o2])   + c0_s[2*o2];
        float b1 = rb*(accb[o2].y - mb2*rs_s[2*o2+1]) + c0_s[2*o2+1];
        *(float2*)&out[(b*CIN + 2*o2)*HW + rem]   = float2{a0, b0};
        *(float2*)&out[(b*CIN + 2*o2+1)*HW + rem] = float2{a1, b1};
    }
}

extern "C" void kernel_launch(void* const* d_in, const int* in_sizes, int n_in,
                              void* d_out, int out_size, void* d_ws, size_t ws_size,
                              hipStream_t stream)
{
    const float* x    = (const float*)d_in[0];
    const float* ng   = (const float*)d_in[1];
    const float* nb   = (const float*)d_in[2];
    const float* ipw  = (const float*)d_in[3];
    const float* cw   = (const float*)d_in[4];
    const float* cb   = (const float*)d_in[5];
    const float* xw   = (const float*)d_in[6];
    const float* dwm  = (const float*)d_in[7];
    const float* dbv  = (const float*)d_in[8];
    const float* Alog = (const float*)d_in[9];
    const float* Dpv  = (const float*)d_in[10];
    const float* mg   = (const float*)d_in[11];
    const float* mb   = (const float*)d_in[12];
    const float* mw   = (const float*)d_in[13];
    const float* ow   = (const float*)d_in[14];
    const float* ob   = (const float*)d_in[15];
    float* out = (float*)d_out;

    const size_t y4_bytes = (size_t)4*BHW*DIN*2;     // 150,994,944 (planar)
    const size_t dl_bytes = (size_t)4*BHW*8;         //  18,874,368
    const size_t bc_bytes = (size_t)4*BHW*32;        //  75,497,472
    const size_t wt_bytes = (size_t)(128*CIN + 64)*4;

    char* ws = (char*)d_ws;
    u16* y4 = (u16*)ws;

    size_t dl_pos = y4_bytes + GUARD;
    size_t bc_pos = dl_pos + dl_bytes + GUARD;
    size_t wt_pos = bc_pos + bc_bytes + GUARD;
    size_t need   = wt_pos + wt_bytes + GUARD;       // ~245.6 MB (proven budget; ws < 321MB per R4)

    if (ws_size < need) {
        hipMemsetAsync(d_out, 0x7F, (size_t)out_size*4, stream);  // diagnosable sentinel
        return;
    }

    // h2 (u after conv) lives inside d_out with UGUARD front guard (128K for
    // 4-deep prefetch overrun of the vertical-scan u stream: 4*24576 = 96K).
    char* h2base = (char*)d_out;                     // data at +UGUARD
    u16*  h2 = (u16*)(h2base + UGUARD);              // 128K + 37.75MB + 9.3MB tail < 47.19 MB

    u16* dlA = (u16*)(ws + dl_pos);
    u16* bcA = (u16*)(ws + bc_pos);
    float* Wt   = (float*)(ws + wt_pos);
    float* rsum = Wt + 128*CIN;
    float* c0   = rsum + 32;

    k_prep  <<<1, 128, 0, stream>>>(ow, mw, mg, mb, ob, Wt, rsum, c0);
    k_lnconv<<<2304, 256, 0, stream>>>(x, ng, nb, ipw, cw, cb, h2);
    k_proj  <<<BHW/512, 256, 0, stream>>>(h2, xw, dlA, bcA);
    k_scan  <<<768, 256, 0, stream>>>(
        h2base, (const char*)(ws + dl_pos - GUARD), (const char*)(ws + bc_pos - GUARD),
        Alog, Dpv, dwm, dbv, (char*)y4);
    k_merge <<<BHW/512, 256, 0, stream>>>(y4, Wt, rsum, c0, out);
}

// Round 10
// 743.410 us; speedup vs baseline: 1.0293x; 1.0227x over previous
//
#include <hip/hip_runtime.h>

typedef unsigned short u16;
typedef unsigned int   u32;
typedef unsigned long long u64;
typedef float f2 __attribute__((ext_vector_type(2)));

#define CIN  20
#define DIN  32
#define BB   4
#define HH   384
#define WW   384
#define HW   147456
#define BHW  589824
#define EPSF 1e-5f
#define GUARD  65536      // streams with <=49152B 4-step overrun
#define UGUARD 131072     // u stream: 4-step overrun 98304 < 128K

__device__ __forceinline__ float bflo(u32 u) {
    union { u32 v; float f; } x; x.v = u << 16; return x.f;
}
__device__ __forceinline__ float bfhi(u32 u) {
    union { u32 v; float f; } x; x.v = u & 0xffff0000u; return x.f;
}
__device__ __forceinline__ float bf2f(u16 h) {
    union { u32 v; float f; } x; x.v = ((u32)h) << 16; return x.f;
}
__device__ __forceinline__ u16 f2bf(float f) {
    union { float f; u32 u; } v; v.f = f;
    u32 u = v.u;
    return (u16)((u + 0x7FFFu + ((u >> 16) & 1u)) >> 16);
}
__device__ __forceinline__ float silu_f(float a) {
    return a / (1.f + __expf(-a));
}
__device__ __forceinline__ float softplus_f(float z) {
    return (z > 15.f) ? z : __logf(1.f + __expf(z));
}

// ---------------- K0: fold merge+out weights ----------------
__global__ void k_prep(const float* __restrict__ ow, const float* __restrict__ mw,
                       const float* __restrict__ mg, const float* __restrict__ mb,
                       const float* __restrict__ ob,
                       float* __restrict__ Wt, float* __restrict__ rsum,
                       float* __restrict__ c0)
{
    __shared__ float mdot[DIN];
    int t = threadIdx.x; // 128 threads
    if (t < DIN) {
        float s = 0.f;
        for (int k = 0; k < 128; ++k) s += mw[t*128 + k] * mb[k];
        mdot[t] = s;
    }
    {
        int k = t;
        for (int o = 0; o < CIN; ++o) {
            float s = 0.f;
            for (int d = 0; d < DIN; ++d) s += ow[o*DIN + d] * mw[d*128 + k];
            Wt[k*CIN + o] = s * mg[k];
        }
    }
    __syncthreads();
    if (t < CIN) {
        float rs = 0.f;
        for (int k = 0; k < 128; ++k) rs += Wt[k*CIN + t];
        rsum[t] = rs;
        float c = ob[t];
        for (int d = 0; d < DIN; ++d) c += ow[t*DIN + d] * mdot[d];
        c0[t] = c;
    }
}

// ---------------- K_LNCONV: fused layernorm+inproj+silu -> 3x3 dwconv+silu ----------------
// 16x16 tile + 1-halo. Phase 1: LN+inproj+silu for 18x18 halo -> LDS f32 tile.
// Phase 2: conv+silu from LDS -> h2 bf16. Eliminates h1 round trip entirely.
// CRITICAL: "#pragma unroll 1" on the phase-1 grid-stride loop. R7/R9 evidence:
// the compiler unrolls the 1-or-2-trip loop and interleaves both iterations'
// 20 x-loads + 32-float accumulators -> 256 VGPR + ~490MB scratch spill
// (R6's straight-line version of the same body had no spill).
#define TS   16
#define HT   18
#define CPAD 36
__global__ __launch_bounds__(256) void k_lnconv(
    const float* __restrict__ x, const float* __restrict__ ng,
    const float* __restrict__ nb, const float* __restrict__ ipw,
    const float* __restrict__ cw, const float* __restrict__ cb,
    u16* __restrict__ h2)
{
    __shared__ __align__(16) float hs[HT*HT*CPAD];      // 46656 B
    __shared__ __align__(16) f2 wln_s[CIN*16];          // 2560 B
    __shared__ float g_s[CIN], b_s[CIN];
    __shared__ __align__(16) f2 wc_s[9*16];             // 1152 B
    __shared__ __align__(16) f2 bc2_s[16];

    int tid = threadIdx.x;
    for (int i = tid; i < CIN*16; i += 256) {
        int c = i >> 4, j2 = i & 15;
        wln_s[i] = f2{ ipw[(2*j2)*CIN + c], ipw[(2*j2+1)*CIN + c] };
    }
    if (tid < CIN) { g_s[tid] = ng[tid]; b_s[tid] = nb[tid]; }
    if (tid < 144) wc_s[tid] = f2{ cw[2*tid], cw[2*tid+1] };
    if (tid >= 144 && tid < 160) {
        int i = tid - 144;
        bc2_s[i] = f2{ cb[2*i], cb[2*i+1] };
    }
    __syncthreads();

    int bx = blockIdx.x;
    int b  = bx / 576, t6 = bx % 576;
    int ty0 = (t6 / 24)*TS, tx0 = (t6 % 24)*TS;

    // ---- phase 1: halo LN+inproj+silu -> LDS (NO cross-iteration unroll) ----
    #pragma unroll 1
    for (int j = tid; j < HT*HT; j += 256) {
        int hy = j / HT, hx = j % HT;
        int gy = ty0 + hy - 1, gx = tx0 + hx - 1;
        float* hp = &hs[(hy*HT + hx)*CPAD];
        if (gy >= 0 && gy < HH && gx >= 0 && gx < WW) {
            int rem = gy*WW + gx;
            float v[CIN];
            float m = 0.f;
            #pragma unroll
            for (int c = 0; c < CIN; ++c) { v[c] = x[(b*CIN + c)*HW + rem]; m += v[c]; }
            m *= (1.f/CIN);
            float var = 0.f;
            #pragma unroll
            for (int c = 0; c < CIN; ++c) { float d = v[c]-m; var += d*d; }
            var *= (1.f/CIN);
            float rstd = rsqrtf(var + EPSF);
            #pragma unroll
            for (int c = 0; c < CIN; ++c) v[c] = (v[c]-m)*rstd*g_s[c] + b_s[c];

            f2 o2[16];
            #pragma unroll
            for (int j2 = 0; j2 < 16; ++j2) o2[j2] = f2{0.f, 0.f};
            #pragma unroll
            for (int c = 0; c < CIN; ++c) {
                f2 vc = { v[c], v[c] };
                const float4* wr = (const float4*)&wln_s[c*16];
                #pragma unroll
                for (int jq = 0; jq < 8; ++jq) {
                    float4 wp = wr[jq];
                    o2[2*jq]   = __builtin_elementwise_fma(f2{wp.x, wp.y}, vc, o2[2*jq]);
                    o2[2*jq+1] = __builtin_elementwise_fma(f2{wp.z, wp.w}, vc, o2[2*jq+1]);
                }
            }
            #pragma unroll
            for (int q = 0; q < 8; ++q) {
                float a0 = silu_f(o2[2*q].x),   a1 = silu_f(o2[2*q].y);
                float a2 = silu_f(o2[2*q+1].x), a3 = silu_f(o2[2*q+1].y);
                *(float4*)&hp[4*q] = make_float4(a0, a1, a2, a3);
            }
        } else {
            #pragma unroll
            for (int q = 0; q < 8; ++q)
                *(float4*)&hp[4*q] = make_float4(0.f, 0.f, 0.f, 0.f);
        }
    }
    __syncthreads();

    // ---- phase 2: conv + silu -> h2 ----
    int ty = tid >> 4, tx = tid & 15;
    int gy = ty0 + ty, gx = tx0 + tx;
    int p  = b*HW + gy*WW + gx;

    f2 acc2[16];
    #pragma unroll
    for (int i = 0; i < 16; ++i) acc2[i] = bc2_s[i];

    #pragma unroll
    for (int k = 0; k < 9; ++k) {
        int dy = k/3, dx = k%3;
        const float* np = &hs[((ty+dy)*HT + (tx+dx))*CPAD];
        const f2* wk = &wc_s[k*16];
        #pragma unroll
        for (int q = 0; q < 8; ++q) {
            float4 t4 = *(const float4*)&np[4*q];
            acc2[2*q]   = __builtin_elementwise_fma(wk[2*q],   f2{t4.x, t4.y}, acc2[2*q]);
            acc2[2*q+1] = __builtin_elementwise_fma(wk[2*q+1], f2{t4.z, t4.w}, acc2[2*q+1]);
        }
    }

    u32 pk[16];
    #pragma unroll
    for (int i = 0; i < 16; ++i) {
        float a = silu_f(acc2[i].x);
        float c = silu_f(acc2[i].y);
        pk[i] = (u32)f2bf(a) | ((u32)f2bf(c) << 16);
    }
    uint4* dst = (uint4*)(h2 + (size_t)p*DIN);
    dst[0] = make_uint4(pk[0],pk[1],pk[2],pk[3]);
    dst[1] = make_uint4(pk[4],pk[5],pk[6],pk[7]);
    dst[2] = make_uint4(pk[8],pk[9],pk[10],pk[11]);
    dst[3] = make_uint4(pk[12],pk[13],pk[14],pk[15]);
}

// ---------------- K3: xdbl -> dl + BC, pk-FMA, 2-pixel register blocking ----------------
__global__ __launch_bounds__(256) void k_proj(
    const u16* __restrict__ h2, const float* __restrict__ xw,
    u16* __restrict__ dlA, u16* __restrict__ bcA)
{
    __shared__ __align__(16) f2 xw2_s[4*DIN*10];
    for (int i = threadIdx.x; i < 4*DIN*10; i += 256) {
        int dir = i / 320, r = i % 320;
        int d = r / 10, j2 = r % 10;
        xw2_s[i] = f2{ xw[(dir*CIN + 2*j2)*DIN + d],
                       xw[(dir*CIN + 2*j2 + 1)*DIN + d] };
    }
    __syncthreads();

    int p = (blockIdx.x*256 + threadIdx.x)*2;
    float ua[DIN], ub[DIN];
    const uint4* src = (const uint4*)(h2 + (size_t)p*DIN);
    #pragma unroll
    for (int q4 = 0; q4 < 4; ++q4) {
        uint4 v = src[q4];
        ua[q4*8+0]=bflo(v.x); ua[q4*8+1]=bfhi(v.x);
        ua[q4*8+2]=bflo(v.y); ua[q4*8+3]=bfhi(v.y);
        ua[q4*8+4]=bflo(v.z); ua[q4*8+5]=bfhi(v.z);
        ua[q4*8+6]=bflo(v.w); ua[q4*8+7]=bfhi(v.w);
        uint4 w = src[q4+4];
        ub[q4*8+0]=bflo(w.x); ub[q4*8+1]=bfhi(w.x);
        ub[q4*8+2]=bflo(w.y); ub[q4*8+3]=bfhi(w.y);
        ub[q4*8+4]=bflo(w.z); ub[q4*8+5]=bfhi(w.z);
        ub[q4*8+6]=bflo(w.w); ub[q4*8+7]=bfhi(w.w);
    }
    #pragma unroll 1
    for (int dir = 0; dir < 4; ++dir) {
        f2 xa[10], xb[10];
        #pragma unroll
        for (int j2 = 0; j2 < 10; ++j2) { xa[j2] = f2{0.f,0.f}; xb[j2] = f2{0.f,0.f}; }
        #pragma unroll
        for (int d = 0; d < DIN; ++d) {
            f2 uda = { ua[d], ua[d] };
            f2 udb = { ub[d], ub[d] };
            const float4* wr = (const float4*)&xw2_s[(dir*DIN + d)*10];
            #pragma unroll
            for (int jq = 0; jq < 5; ++jq) {
                float4 wp = wr[jq];
                f2 wlo = {wp.x, wp.y}, whi = {wp.z, wp.w};
                xa[2*jq]   = __builtin_elementwise_fma(wlo, uda, xa[2*jq]);
                xa[2*jq+1] = __builtin_elementwise_fma(whi, uda, xa[2*jq+1]);
                xb[2*jq]   = __builtin_elementwise_fma(wlo, udb, xb[2*jq]);
                xb[2*jq+1] = __builtin_elementwise_fma(whi, udb, xb[2*jq+1]);
            }
        }
        u32 pa[10], pb[10];
        #pragma unroll
        for (int i = 0; i < 10; ++i) {
            pa[i] = (u32)f2bf(xa[i].x) | ((u32)f2bf(xa[i].y) << 16);
            pb[i] = (u32)f2bf(xb[i].x) | ((u32)f2bf(xb[i].y) << 16);
        }
        // dl: two adjacent 8B records -> one uint4 (16B aligned: p even)
        *(uint4*)(dlA + (size_t)(dir*BHW + p)*4) = make_uint4(pa[0], pa[1], pb[0], pb[1]);
        // bc: two adjacent 32B records -> four uint4
        uint4* bcd = (uint4*)(bcA + (size_t)(dir*BHW + p)*16);
        bcd[0] = make_uint4(pa[2], pa[3], pa[4], pa[5]);   // A: B0..B7
        bcd[1] = make_uint4(pa[6], pa[7], pa[8], pa[9]);   // A: C0..C7
        bcd[2] = make_uint4(pb[2], pb[3], pb[4], pb[5]);   // B: B0..B7
        bcd[3] = make_uint4(pb[6], pb[7], pb[8], pb[9]);   // B: C0..C7
    }
}

// ---------------- K4: 4-direction selective scan [R2/R6 champion, unchanged] ----------------
__global__ __launch_bounds__(256) void k_scan(
    const char* __restrict__ h2b,   // u data at +UGUARD
    const char* __restrict__ dlb_,  // dl data at +GUARD (8B records)
    const char* __restrict__ bcb_,  // (B,C) data at +GUARD (32B records)
    const float* __restrict__ Alog, const float* __restrict__ Dp,
    const float* __restrict__ dwm,  const float* __restrict__ dbv,
    char* __restrict__ y4b)         // planar (dir, pixel, 32) bf16
{
    int tid  = blockIdx.x*256 + threadIdx.x;
    int wv   = tid >> 6, lane = tid & 63;
    int half = lane >> 5, d = lane & 31;
    int dir  = wv / 768;                 // uniform per wave
    int s    = (wv % 768)*2 + half;
    int b    = s / 384, r = s % 384;

    int p0, stp;
    if (dir == 0)      { p0 = b*HW + r*WW;           stp = 1;  }
    else if (dir == 1) { p0 = b*HW + r*WW + (WW-1);  stp = -1; }
    else if (dir == 2) { p0 = b*HW + r;              stp = WW; }
    else               { p0 = b*HW + (HH-1)*WW + r;  stp = -WW;}

    float Av[8];
    bool okl = true;
    #pragma unroll
    for (int j = 0; j < 8; ++j) {
        float e = __expf(Alog[(dir*DIN + d)*8 + j]);
        Av[j] = -e;
        okl = okl && (__builtin_fabsf(e - (float)(j+1)) < 2e-3f);
    }
    bool fast = (__ballot(okl) == ~0ull);

    float Dd  = Dp[dir*DIN + d];
    float dw0 = dwm[(dir*DIN + d)*4 + 0], dw1 = dwm[(dir*DIN + d)*4 + 1];
    float dw2 = dwm[(dir*DIN + d)*4 + 2], dw3 = dwm[(dir*DIN + d)*4 + 3];
    float dbc = dbv[dir*DIN + d];

    u32 uo = UGUARD + (u32)((p0*DIN + d)*2);           int su = stp*DIN*2;
    u32 yo = (u32)((dir*BHW + p0)*64 + d*2);           int sy = stp*64;
    u32 c1 = GUARD + (u32)((dir*BHW + p0)*8);          int s1 = stp*8;
    u32 c2 = GUARD + (u32)((dir*BHW + p0)*32);         int s2 = stp*32;

    u16 ub[4]; uint2 dlr[4]; uint4 B4[4], C4[4];
    u32 fu = uo, f1 = c1, f2o = c2;

    auto fetch = [&](int sl) {
        ub[sl]  = *(const u16*)(h2b + fu);
        dlr[sl] = *(const uint2*)(dlb_ + f1);
        B4[sl]  = *(const uint4*)(bcb_ + f2o);
        C4[sl]  = *(const uint4*)(bcb_ + f2o + 16);
        fu += (u32)su; f1 += (u32)s1; f2o += (u32)s2;
    };

    #pragma unroll
    for (int i = 0; i < 4; ++i) fetch(i);

    f2 h0 = {0.f,0.f}, h1v = {0.f,0.f}, h2v = {0.f,0.f}, h3 = {0.f,0.f};

    if (fast) {
        f2 a01, a23, a45, a67;
        f2 Bq0, Bq1, Bq2, Bq3;
        f2 Cp0, Cp1, Cp2, Cp3;
        float ydc;

        auto prep = [&](int sl) {
            float uu = bf2f(ub[sl]);
            uint2 dl = dlr[sl];
            uint4 Bv = B4[sl], Cv = C4[sl];
            float z = dbc + dw0*bflo(dl.x) + dw1*bfhi(dl.x)
                          + dw2*bflo(dl.y) + dw3*bfhi(dl.y);
            z = fminf(z, 80.f);
            float ez = __expf(z);
            float w  = 1.f + ez;
            float rr = __builtin_amdgcn_rcpf(w);   // = exp(-dt)
            float dt = __logf(w);                  // softplus(z); parallel with rcp
            float r2 = rr*rr;
            f2 rr2 = {r2, r2};
            f2 t01 = {rr, r2};
            a01 = t01;
            a23 = t01*rr2;
            a45 = a23*rr2;
            a67 = a45*rr2;
            float dtu = dt*uu;
            f2 du2 = {dtu, dtu};
            f2 Bp0 = { bflo(Bv.x), bfhi(Bv.x) }, Bp1 = { bflo(Bv.y), bfhi(Bv.y) };
            f2 Bp2 = { bflo(Bv.z), bfhi(Bv.z) }, Bp3 = { bflo(Bv.w), bfhi(Bv.w) };
            Bq0 = du2*Bp0; Bq1 = du2*Bp1; Bq2 = du2*Bp2; Bq3 = du2*Bp3;
            f2 c0 = { bflo(Cv.x), bfhi(Cv.x) }, c1v = { bflo(Cv.y), bfhi(Cv.y) };
            f2 c2v = { bflo(Cv.z), bfhi(Cv.z) }, c3 = { bflo(Cv.w), bfhi(Cv.w) };
            Cp0 = c0; Cp1 = c1v; Cp2 = c2v; Cp3 = c3;
            ydc = Dd*uu;
        };

        prep(0);

        #pragma unroll 4
        for (int t = 0; t < 384; ++t) {
            int sl = t & 3;
            fetch(sl);

            h0  = __builtin_elementwise_fma(a01, h0,  Bq0);
            h1v = __builtin_elementwise_fma(a23, h1v, Bq1);
            h2v = __builtin_elementwise_fma(a45, h2v, Bq2);
            h3  = __builtin_elementwise_fma(a67, h3,  Bq3);

            f2 yv = Cp0*h0;
            yv = __builtin_elementwise_fma(Cp1, h1v, yv);
            yv = __builtin_elementwise_fma(Cp2, h2v, yv);
            yv = __builtin_elementwise_fma(Cp3, h3,  yv);
            float y = yv.x + yv.y + ydc;

            prep((t+1) & 3);

            *(u16*)(y4b + yo) = f2bf(y);
            yo += (u32)sy;
        }
    } else {
        f2 A2[4];
        #pragma unroll
        for (int j = 0; j < 4; ++j) { A2[j].x = Av[2*j]; A2[j].y = Av[2*j+1]; }
        #pragma unroll 4
        for (int t = 0; t < 384; ++t) {
            int sl = t & 3;
            float uu = bf2f(ub[sl]);
            uint2 dl = dlr[sl];
            uint4 Bv = B4[sl], Cv = C4[sl];
            fetch(sl);

            float z = dbc + dw0*bflo(dl.x) + dw1*bfhi(dl.x)
                          + dw2*bflo(dl.y) + dw3*bfhi(dl.y);
            float dt = softplus_f(z);
            f2 dt2 = {dt, dt};
            f2 e0 = dt2*A2[0], e1 = dt2*A2[1], e2 = dt2*A2[2], e3 = dt2*A2[3];
            f2 a01 = { __expf(e0.x), __expf(e0.y) };
            f2 a23 = { __expf(e1.x), __expf(e1.y) };
            f2 a45 = { __expf(e2.x), __expf(e2.y) };
            f2 a67 = { __expf(e3.x), __expf(e3.y) };

            float dtu = dt*uu;
            f2 du2 = {dtu, dtu};
            f2 Bp0 = { bflo(Bv.x), bfhi(Bv.x) }, Bp1 = { bflo(Bv.y), bfhi(Bv.y) };
            f2 Bp2 = { bflo(Bv.z), bfhi(Bv.z) }, Bp3 = { bflo(Bv.w), bfhi(Bv.w) };
            f2 Cp0 = { bflo(Cv.x), bfhi(Cv.x) }, Cp1 = { bflo(Cv.y), bfhi(Cv.y) };
            f2 Cp2 = { bflo(Cv.z), bfhi(Cv.z) }, Cp3 = { bflo(Cv.w), bfhi(Cv.w) };

            h0  = __builtin_elementwise_fma(a01, h0,  du2*Bp0);
            h1v = __builtin_elementwise_fma(a23, h1v, du2*Bp1);
            h2v = __builtin_elementwise_fma(a45, h2v, du2*Bp2);
            h3  = __builtin_elementwise_fma(a67, h3,  du2*Bp3);

            f2 yv = Cp0*h0;
            yv = __builtin_elementwise_fma(Cp1, h1v, yv);
            yv = __builtin_elementwise_fma(Cp2, h2v, yv);
            yv = __builtin_elementwise_fma(Cp3, h3,  yv);

            float y = yv.x + yv.y + Dd*uu;
            *(u16*)(y4b + yo) = f2bf(y);
            yo += (u32)sy;
        }
    }
}

// ---------------- K5: LN(128) + folded 128->20 + transpose, 2-pixel blocking ----------------
__global__ __launch_bounds__(256) void k_merge(
    const u16* __restrict__ y4, const float* __restrict__ Wt,
    const float* __restrict__ rsum, const float* __restrict__ c0,
    float* __restrict__ out)
{
    __shared__ __align__(16) f2 Wt2_s[128*10];   // [k][o2] = {Wt[k][2o2], Wt[k][2o2+1]}
    __shared__ float rs_s[CIN], c0_s[CIN];
    for (int i = threadIdx.x; i < 128*10; i += 256) {
        int k = i / 10, o2 = i % 10;
        Wt2_s[i] = f2{ Wt[k*CIN + 2*o2], Wt[k*CIN + 2*o2 + 1] };
    }
    if (threadIdx.x < CIN) { rs_s[threadIdx.x] = rsum[threadIdx.x]; c0_s[threadIdx.x] = c0[threadIdx.x]; }
    __syncthreads();

    int p = (blockIdx.x*256 + threadIdx.x)*2;
    int b = p / HW, rem = p % HW;    // p even, HW even: pair never straddles b

    float s1a = 0.f, s2a = 0.f, s1b = 0.f, s2b = 0.f;
    f2 acca[10], accb[10];
    #pragma unroll
    for (int o2 = 0; o2 < 10; ++o2) { acca[o2] = f2{0.f,0.f}; accb[o2] = f2{0.f,0.f}; }

    #pragma unroll 1
    for (int dirk = 0; dirk < 4; ++dirk) {
        const uint4* src = (const uint4*)(y4 + ((size_t)dirk*BHW + p)*32);
        #pragma unroll
        for (int q4 = 0; q4 < 4; ++q4) {
            uint4 va = src[q4];
            uint4 vb = src[q4+4];
            u32 wa[4] = {va.x, va.y, va.z, va.w};
            u32 wb[4] = {vb.x, vb.y, vb.z, vb.w};
            #pragma unroll
            for (int i = 0; i < 4; ++i) {
                int k = dirk*32 + q4*8 + i*2;
                float aa = bflo(wa[i]); float ca = bfhi(wa[i]);
                float ab = bflo(wb[i]); float cb = bfhi(wb[i]);
                s1a += aa + ca; s2a += aa*aa + ca*ca;
                s1b += ab + cb; s2b += ab*ab + cb*cb;
                f2 afa = {aa, aa}, cfa = {ca, ca};
                f2 afb = {ab, ab}, cfb = {cb, cb};
                const float4* w0 = (const float4*)&Wt2_s[k*10];
                const float4* w1 = (const float4*)&Wt2_s[(k+1)*10];
                #pragma unroll
                for (int jq = 0; jq < 5; ++jq) {
                    float4 x0 = w0[jq], x1 = w1[jq];
                    f2 x0lo = {x0.x, x0.y}, x0hi = {x0.z, x0.w};
                    f2 x1lo = {x1.x, x1.y}, x1hi = {x1.z, x1.w};
                    acca[2*jq]   = __builtin_elementwise_fma(x0lo, afa, acca[2*jq]);
                    acca[2*jq]   = __builtin_elementwise_fma(x1lo, cfa, acca[2*jq]);
                    acca[2*jq+1] = __builtin_elementwise_fma(x0hi, afa, acca[2*jq+1]);
                    acca[2*jq+1] = __builtin_elementwise_fma(x1hi, cfa, acca[2*jq+1]);
                    accb[2*jq]   = __builtin_elementwise_fma(x0lo, afb, accb[2*jq]);
                    accb[2*jq]   = __builtin_elementwise_fma(x1lo, cfb, accb[2*jq]);
                    accb[2*jq+1] = __builtin_elementwise_fma(x0hi, afb, accb[2*jq+1]);
                    accb[2*jq+1] = __builtin_elementwise_fma(x1hi, cfb, accb[2*jq+1]);
                }
            }
        }
    }
    float ma = s1a*(1.f/128.f);
    float va = s2a*(1.f/128.f) - ma*ma;
    float ra = rsqrtf(va + EPSF);
    float mb2 = s1b*(1.f/128.f);
    float vb2 = s2b*(1.f/128.f) - mb2*mb2;
    float rb = rsqrtf(vb2 + EPSF);
    #pragma unroll
    for (int o2 = 0; o2 < 10; ++o2) {
        float a0 = ra*(acca[o2].x - ma*rs_s[2*o2])    + c0_s[2*o2];
        float a1 = ra*(acca[o2].y - ma*rs_s[2*o2+1])  + c0_s[2*o2+1];
        float b0 = rb*(accb[o2].x - mb2*rs_s[2*o2])   + c0_s[2*o2];
        float b1 = rb*(accb[o2].y - mb2*rs_s[2*o2+1]) + c0_s[2*o2+1];
        *(float2*)&out[(b*CIN + 2*o2)*HW + rem]   = float2{a0, b0};
        *(float2*)&out[(b*CIN + 2*o2+1)*HW + rem] = float2{a1, b1};
    }
}

extern "C" void kernel_launch(void* const* d_in, const int* in_sizes, int n_in,
                              void* d_out, int out_size, void* d_ws, size_t ws_size,
                              hipStream_t stream)
{
    const float* x    = (const float*)d_in[0];
    const float* ng   = (const float*)d_in[1];
    const float* nb   = (const float*)d_in[2];
    const float* ipw  = (const float*)d_in[3];
    const float* cw   = (const float*)d_in[4];
    const float* cb   = (const float*)d_in[5];
    const float* xw   = (const float*)d_in[6];
    const float* dwm  = (const float*)d_in[7];
    const float* dbv  = (const float*)d_in[8];
    const float* Alog = (const float*)d_in[9];
    const float* Dpv  = (const float*)d_in[10];
    const float* mg   = (const float*)d_in[11];
    const float* mb   = (const float*)d_in[12];
    const float* mw   = (const float*)d_in[13];
    const float* ow   = (const float*)d_in[14];
    const float* ob   = (const float*)d_in[15];
    float* out = (float*)d_out;

    const size_t y4_bytes = (size_t)4*BHW*DIN*2;     // 150,994,944 (planar)
    const size_t dl_bytes = (size_t)4*BHW*8;         //  18,874,368
    const size_t bc_bytes = (size_t)4*BHW*32;        //  75,497,472
    const size_t wt_bytes = (size_t)(128*CIN + 64)*4;

    char* ws = (char*)d_ws;
    u16* y4 = (u16*)ws;

    size_t dl_pos = y4_bytes + GUARD;
    size_t bc_pos = dl_pos + dl_bytes + GUARD;
    size_t wt_pos = bc_pos + bc_bytes + GUARD;
    size_t need   = wt_pos + wt_bytes + GUARD;       // ~245.6 MB (proven budget; ws < 321MB per R4)

    if (ws_size < need) {
        hipMemsetAsync(d_out, 0x7F, (size_t)out_size*4, stream);  // diagnosable sentinel
        return;
    }

    // h2 (u after conv) lives inside d_out with UGUARD front guard (128K for
    // 4-deep prefetch overrun of the vertical-scan u stream: 4*24576 = 96K).
    char* h2base = (char*)d_out;                     // data at +UGUARD
    u16*  h2 = (u16*)(h2base + UGUARD);              // 128K + 37.75MB + 9.3MB tail < 47.19 MB

    u16* dlA = (u16*)(ws + dl_pos);
    u16* bcA = (u16*)(ws + bc_pos);
    float* Wt   = (float*)(ws + wt_pos);
    float* rsum = Wt + 128*CIN;
    float* c0   = rsum + 32;

    k_prep  <<<1, 128, 0, stream>>>(ow, mw, mg, mb, ob, Wt, rsum, c0);
    k_lnconv<<<2304, 256, 0, stream>>>(x, ng, nb, ipw, cw, cb, h2);
    k_proj  <<<BHW/512, 256, 0, stream>>>(h2, xw, dlA, bcA);
    k_scan  <<<768, 256, 0, stream>>>(
        h2base, (const char*)(ws + dl_pos - GUARD), (const char*)(ws + bc_pos - GUARD),
        Alog, Dpv, dwm, dbv, (char*)y4);
    k_merge <<<BHW/512, 256, 0, stream>>>(y4, Wt, rsum, c0, out);
}

// Round 11
// 484.999 us; speedup vs baseline: 1.5777x; 1.5328x over previous
//
#include <hip/hip_runtime.h>

typedef unsigned short u16;
typedef unsigned int   u32;
typedef unsigned long long u64;
typedef float f2 __attribute__((ext_vector_type(2)));

#define CIN  20
#define DIN  32
#define BB   4
#define HH   384
#define WW   384
#define HW   147456
#define BHW  589824
#define EPSF 1e-5f
#define GUARD  65536      // streams with <=49152B 4-step overrun
#define UGUARD 131072     // u stream: 4-step overrun 98304 < 128K

__device__ __forceinline__ float bflo(u32 u) {
    union { u32 v; float f; } x; x.v = u << 16; return x.f;
}
__device__ __forceinline__ float bfhi(u32 u) {
    union { u32 v; float f; } x; x.v = u & 0xffff0000u; return x.f;
}
__device__ __forceinline__ float bf2f(u16 h) {
    union { u32 v; float f; } x; x.v = ((u32)h) << 16; return x.f;
}
__device__ __forceinline__ u16 f2bf(float f) {
    union { float f; u32 u; } v; v.f = f;
    u32 u = v.u;
    return (u16)((u + 0x7FFFu + ((u >> 16) & 1u)) >> 16);
}
__device__ __forceinline__ float silu_f(float a) {
    return a / (1.f + __expf(-a));
}
__device__ __forceinline__ float softplus_f(float z) {
    return (z > 15.f) ? z : __logf(1.f + __expf(z));
}

// ---------------- K0: fold merge+out weights ----------------
__global__ void k_prep(const float* __restrict__ ow, const float* __restrict__ mw,
                       const float* __restrict__ mg, const float* __restrict__ mb,
                       const float* __restrict__ ob,
                       float* __restrict__ Wt, float* __restrict__ rsum,
                       float* __restrict__ c0)
{
    __shared__ float mdot[DIN];
    int t = threadIdx.x; // 128 threads
    if (t < DIN) {
        float s = 0.f;
        for (int k = 0; k < 128; ++k) s += mw[t*128 + k] * mb[k];
        mdot[t] = s;
    }
    {
        int k = t;
        for (int o = 0; o < CIN; ++o) {
            float s = 0.f;
            for (int d = 0; d < DIN; ++d) s += ow[o*DIN + d] * mw[d*128 + k];
            Wt[k*CIN + o] = s * mg[k];
        }
    }
    __syncthreads();
    if (t < CIN) {
        float rs = 0.f;
        for (int k = 0; k < 128; ++k) rs += Wt[k*CIN + t];
        rsum[t] = rs;
        float c = ob[t];
        for (int d = 0; d < DIN; ++d) c += ow[t*DIN + d] * mdot[d];
        c0[t] = c;
    }
}

// ---------------- K_LNCONV: fused layernorm+inproj+silu -> 3x3 dwconv+silu ----------------
// 16x16 tile + 1-halo. Phase 1 handles the 324 halo pixels as TWO STRAIGHT-LINE
// blocks separated by __syncthreads() (324 = 256 + 68) — NO grid-stride loop.
// R9/R10 evidence: any loop around the LN body lets LICM hoist the 320-float
// wln_s weight array out of the loop -> VGPR pinned at 256 + ~490MB scratch
// spill ("#pragma unroll 1" did NOT stop the hoist). Barriers are memory
// fences: loads cannot be hoisted across, so each block's register lifetime
// is the proven R6 straight-line footprint (~100 VGPR).
#define TS   16
#define HT   18
#define CPAD 36
__global__ __launch_bounds__(256) void k_lnconv(
    const float* __restrict__ x, const float* __restrict__ ng,
    const float* __restrict__ nb, const float* __restrict__ ipw,
    const float* __restrict__ cw, const float* __restrict__ cb,
    u16* __restrict__ h2)
{
    __shared__ __align__(16) float hs[HT*HT*CPAD];      // 46656 B
    __shared__ __align__(16) f2 wln_s[CIN*16];          // 2560 B
    __shared__ float g_s[CIN], b_s[CIN];
    __shared__ __align__(16) f2 wc_s[9*16];             // 1152 B
    __shared__ __align__(16) f2 bc2_s[16];

    int tid = threadIdx.x;
    for (int i = tid; i < CIN*16; i += 256) {
        int c = i >> 4, j2 = i & 15;
        wln_s[i] = f2{ ipw[(2*j2)*CIN + c], ipw[(2*j2+1)*CIN + c] };
    }
    if (tid < CIN) { g_s[tid] = ng[tid]; b_s[tid] = nb[tid]; }
    if (tid < 144) wc_s[tid] = f2{ cw[2*tid], cw[2*tid+1] };
    if (tid >= 144 && tid < 160) {
        int i = tid - 144;
        bc2_s[i] = f2{ cb[2*i], cb[2*i+1] };
    }
    __syncthreads();

    int bx = blockIdx.x;
    int b  = bx / 576, t6 = bx % 576;
    int ty0 = (t6 / 24)*TS, tx0 = (t6 % 24)*TS;

    auto do_pixel = [&](int j) {
        int hy = j / HT, hx = j % HT;
        int gy = ty0 + hy - 1, gx = tx0 + hx - 1;
        float* hp = &hs[(hy*HT + hx)*CPAD];
        if (gy >= 0 && gy < HH && gx >= 0 && gx < WW) {
            int rem = gy*WW + gx;
            float v[CIN];
            float m = 0.f;
            #pragma unroll
            for (int c = 0; c < CIN; ++c) { v[c] = x[(b*CIN + c)*HW + rem]; m += v[c]; }
            m *= (1.f/CIN);
            float var = 0.f;
            #pragma unroll
            for (int c = 0; c < CIN; ++c) { float d = v[c]-m; var += d*d; }
            var *= (1.f/CIN);
            float rstd = rsqrtf(var + EPSF);
            #pragma unroll
            for (int c = 0; c < CIN; ++c) v[c] = (v[c]-m)*rstd*g_s[c] + b_s[c];

            f2 o2[16];
            #pragma unroll
            for (int j2 = 0; j2 < 16; ++j2) o2[j2] = f2{0.f, 0.f};
            #pragma unroll
            for (int c = 0; c < CIN; ++c) {
                f2 vc = { v[c], v[c] };
                const float4* wr = (const float4*)&wln_s[c*16];
                #pragma unroll
                for (int jq = 0; jq < 8; ++jq) {
                    float4 wp = wr[jq];
                    o2[2*jq]   = __builtin_elementwise_fma(f2{wp.x, wp.y}, vc, o2[2*jq]);
                    o2[2*jq+1] = __builtin_elementwise_fma(f2{wp.z, wp.w}, vc, o2[2*jq+1]);
                }
            }
            #pragma unroll
            for (int q = 0; q < 8; ++q) {
                float a0 = silu_f(o2[2*q].x),   a1 = silu_f(o2[2*q].y);
                float a2 = silu_f(o2[2*q+1].x), a3 = silu_f(o2[2*q+1].y);
                *(float4*)&hp[4*q] = make_float4(a0, a1, a2, a3);
            }
        } else {
            #pragma unroll
            for (int q = 0; q < 8; ++q)
                *(float4*)&hp[4*q] = make_float4(0.f, 0.f, 0.f, 0.f);
        }
    };

    // ---- phase 1a: halo pixels 0..255 (straight-line, one per thread) ----
    do_pixel(tid);
    __syncthreads();          // fence: prevents hoisting 1b's loads / overlap of live ranges
    // ---- phase 1b: halo pixels 256..323 ----
    if (tid < HT*HT - 256) do_pixel(256 + tid);
    __syncthreads();

    // ---- phase 2: conv + silu -> h2 ----
    int ty = tid >> 4, tx = tid & 15;
    int gy = ty0 + ty, gx = tx0 + tx;
    int p  = b*HW + gy*WW + gx;

    f2 acc2[16];
    #pragma unroll
    for (int i = 0; i < 16; ++i) acc2[i] = bc2_s[i];

    #pragma unroll
    for (int k = 0; k < 9; ++k) {
        int dy = k/3, dx = k%3;
        const float* np = &hs[((ty+dy)*HT + (tx+dx))*CPAD];
        const f2* wk = &wc_s[k*16];
        #pragma unroll
        for (int q = 0; q < 8; ++q) {
            float4 t4 = *(const float4*)&np[4*q];
            acc2[2*q]   = __builtin_elementwise_fma(wk[2*q],   f2{t4.x, t4.y}, acc2[2*q]);
            acc2[2*q+1] = __builtin_elementwise_fma(wk[2*q+1], f2{t4.z, t4.w}, acc2[2*q+1]);
        }
    }

    u32 pk[16];
    #pragma unroll
    for (int i = 0; i < 16; ++i) {
        float a = silu_f(acc2[i].x);
        float c = silu_f(acc2[i].y);
        pk[i] = (u32)f2bf(a) | ((u32)f2bf(c) << 16);
    }
    uint4* dst = (uint4*)(h2 + (size_t)p*DIN);
    dst[0] = make_uint4(pk[0],pk[1],pk[2],pk[3]);
    dst[1] = make_uint4(pk[4],pk[5],pk[6],pk[7]);
    dst[2] = make_uint4(pk[8],pk[9],pk[10],pk[11]);
    dst[3] = make_uint4(pk[12],pk[13],pk[14],pk[15]);
}

// ---------------- K3: xdbl -> dl (8B/rec) + BC (32B/rec), pk-FMA [R6 champion] ----------------
__global__ __launch_bounds__(256) void k_proj(
    const u16* __restrict__ h2, const float* __restrict__ xw,
    u16* __restrict__ dlA, u16* __restrict__ bcA)
{
    __shared__ __align__(16) f2 xw2_s[4*DIN*10];
    for (int i = threadIdx.x; i < 4*DIN*10; i += 256) {
        int dir = i / 320, r = i % 320;
        int d = r / 10, j2 = r % 10;
        xw2_s[i] = f2{ xw[(dir*CIN + 2*j2)*DIN + d],
                       xw[(dir*CIN + 2*j2 + 1)*DIN + d] };
    }
    __syncthreads();

    int p = blockIdx.x*256 + threadIdx.x;
    float u[DIN];
    const uint4* src = (const uint4*)(h2 + (size_t)p*DIN);
    #pragma unroll
    for (int q4 = 0; q4 < 4; ++q4) {
        uint4 v = src[q4];
        u[q4*8+0]=bflo(v.x); u[q4*8+1]=bfhi(v.x);
        u[q4*8+2]=bflo(v.y); u[q4*8+3]=bfhi(v.y);
        u[q4*8+4]=bflo(v.z); u[q4*8+5]=bfhi(v.z);
        u[q4*8+6]=bflo(v.w); u[q4*8+7]=bfhi(v.w);
    }
    #pragma unroll 1
    for (int dir = 0; dir < 4; ++dir) {
        f2 xd2[10];
        #pragma unroll
        for (int j2 = 0; j2 < 10; ++j2) xd2[j2] = f2{0.f, 0.f};
        #pragma unroll
        for (int d = 0; d < DIN; ++d) {
            f2 ud = { u[d], u[d] };
            const float4* wr = (const float4*)&xw2_s[(dir*DIN + d)*10];
            #pragma unroll
            for (int jq = 0; jq < 5; ++jq) {
                float4 wp = wr[jq];
                xd2[2*jq]   = __builtin_elementwise_fma(f2{wp.x, wp.y}, ud, xd2[2*jq]);
                xd2[2*jq+1] = __builtin_elementwise_fma(f2{wp.z, wp.w}, ud, xd2[2*jq+1]);
            }
        }
        u32 pk[10];
        #pragma unroll
        for (int i = 0; i < 10; ++i)
            pk[i] = (u32)f2bf(xd2[i].x) | ((u32)f2bf(xd2[i].y) << 16);
        *(uint2*)(dlA + (size_t)(dir*BHW + p)*4) = make_uint2(pk[0], pk[1]);
        uint4* bcd = (uint4*)(bcA + (size_t)(dir*BHW + p)*16);
        bcd[0] = make_uint4(pk[2], pk[3], pk[4], pk[5]);   // B0..B7
        bcd[1] = make_uint4(pk[6], pk[7], pk[8], pk[9]);   // C0..C7
    }
}

// ---------------- K4: 4-direction selective scan [R2/R6 champion, unchanged] ----------------
__global__ __launch_bounds__(256) void k_scan(
    const char* __restrict__ h2b,   // u data at +UGUARD
    const char* __restrict__ dlb_,  // dl data at +GUARD (8B records)
    const char* __restrict__ bcb_,  // (B,C) data at +GUARD (32B records)
    const float* __restrict__ Alog, const float* __restrict__ Dp,
    const float* __restrict__ dwm,  const float* __restrict__ dbv,
    char* __restrict__ y4b)         // planar (dir, pixel, 32) bf16
{
    int tid  = blockIdx.x*256 + threadIdx.x;
    int wv   = tid >> 6, lane = tid & 63;
    int half = lane >> 5, d = lane & 31;
    int dir  = wv / 768;                 // uniform per wave
    int s    = (wv % 768)*2 + half;
    int b    = s / 384, r = s % 384;

    int p0, stp;
    if (dir == 0)      { p0 = b*HW + r*WW;           stp = 1;  }
    else if (dir == 1) { p0 = b*HW + r*WW + (WW-1);  stp = -1; }
    else if (dir == 2) { p0 = b*HW + r;              stp = WW; }
    else               { p0 = b*HW + (HH-1)*WW + r;  stp = -WW;}

    float Av[8];
    bool okl = true;
    #pragma unroll
    for (int j = 0; j < 8; ++j) {
        float e = __expf(Alog[(dir*DIN + d)*8 + j]);
        Av[j] = -e;
        okl = okl && (__builtin_fabsf(e - (float)(j+1)) < 2e-3f);
    }
    bool fast = (__ballot(okl) == ~0ull);

    float Dd  = Dp[dir*DIN + d];
    float dw0 = dwm[(dir*DIN + d)*4 + 0], dw1 = dwm[(dir*DIN + d)*4 + 1];
    float dw2 = dwm[(dir*DIN + d)*4 + 2], dw3 = dwm[(dir*DIN + d)*4 + 3];
    float dbc = dbv[dir*DIN + d];

    u32 uo = UGUARD + (u32)((p0*DIN + d)*2);           int su = stp*DIN*2;
    u32 yo = (u32)((dir*BHW + p0)*64 + d*2);           int sy = stp*64;
    u32 c1 = GUARD + (u32)((dir*BHW + p0)*8);          int s1 = stp*8;
    u32 c2 = GUARD + (u32)((dir*BHW + p0)*32);         int s2 = stp*32;

    u16 ub[4]; uint2 dlr[4]; uint4 B4[4], C4[4];
    u32 fu = uo, f1 = c1, f2o = c2;

    auto fetch = [&](int sl) {
        ub[sl]  = *(const u16*)(h2b + fu);
        dlr[sl] = *(const uint2*)(dlb_ + f1);
        B4[sl]  = *(const uint4*)(bcb_ + f2o);
        C4[sl]  = *(const uint4*)(bcb_ + f2o + 16);
        fu += (u32)su; f1 += (u32)s1; f2o += (u32)s2;
    };

    #pragma unroll
    for (int i = 0; i < 4; ++i) fetch(i);

    f2 h0 = {0.f,0.f}, h1v = {0.f,0.f}, h2v = {0.f,0.f}, h3 = {0.f,0.f};

    if (fast) {
        f2 a01, a23, a45, a67;
        f2 Bq0, Bq1, Bq2, Bq3;
        f2 Cp0, Cp1, Cp2, Cp3;
        float ydc;

        auto prep = [&](int sl) {
            float uu = bf2f(ub[sl]);
            uint2 dl = dlr[sl];
            uint4 Bv = B4[sl], Cv = C4[sl];
            float z = dbc + dw0*bflo(dl.x) + dw1*bfhi(dl.x)
                          + dw2*bflo(dl.y) + dw3*bfhi(dl.y);
            z = fminf(z, 80.f);
            float ez = __expf(z);
            float w  = 1.f + ez;
            float rr = __builtin_amdgcn_rcpf(w);   // = exp(-dt)
            float dt = __logf(w);                  // softplus(z); parallel with rcp
            float r2 = rr*rr;
            f2 rr2 = {r2, r2};
            f2 t01 = {rr, r2};
            a01 = t01;
            a23 = t01*rr2;
            a45 = a23*rr2;
            a67 = a45*rr2;
            float dtu = dt*uu;
            f2 du2 = {dtu, dtu};
            f2 Bp0 = { bflo(Bv.x), bfhi(Bv.x) }, Bp1 = { bflo(Bv.y), bfhi(Bv.y) };
            f2 Bp2 = { bflo(Bv.z), bfhi(Bv.z) }, Bp3 = { bflo(Bv.w), bfhi(Bv.w) };
            Bq0 = du2*Bp0; Bq1 = du2*Bp1; Bq2 = du2*Bp2; Bq3 = du2*Bp3;
            f2 c0 = { bflo(Cv.x), bfhi(Cv.x) }, c1v = { bflo(Cv.y), bfhi(Cv.y) };
            f2 c2v = { bflo(Cv.z), bfhi(Cv.z) }, c3 = { bflo(Cv.w), bfhi(Cv.w) };
            Cp0 = c0; Cp1 = c1v; Cp2 = c2v; Cp3 = c3;
            ydc = Dd*uu;
        };

        prep(0);

        #pragma unroll 4
        for (int t = 0; t < 384; ++t) {
            int sl = t & 3;
            fetch(sl);

            h0  = __builtin_elementwise_fma(a01, h0,  Bq0);
            h1v = __builtin_elementwise_fma(a23, h1v, Bq1);
            h2v = __builtin_elementwise_fma(a45, h2v, Bq2);
            h3  = __builtin_elementwise_fma(a67, h3,  Bq3);

            f2 yv = Cp0*h0;
            yv = __builtin_elementwise_fma(Cp1, h1v, yv);
            yv = __builtin_elementwise_fma(Cp2, h2v, yv);
            yv = __builtin_elementwise_fma(Cp3, h3,  yv);
            float y = yv.x + yv.y + ydc;

            prep((t+1) & 3);

            *(u16*)(y4b + yo) = f2bf(y);
            yo += (u32)sy;
        }
    } else {
        f2 A2[4];
        #pragma unroll
        for (int j = 0; j < 4; ++j) { A2[j].x = Av[2*j]; A2[j].y = Av[2*j+1]; }
        #pragma unroll 4
        for (int t = 0; t < 384; ++t) {
            int sl = t & 3;
            float uu = bf2f(ub[sl]);
            uint2 dl = dlr[sl];
            uint4 Bv = B4[sl], Cv = C4[sl];
            fetch(sl);

            float z = dbc + dw0*bflo(dl.x) + dw1*bfhi(dl.x)
                          + dw2*bflo(dl.y) + dw3*bfhi(dl.y);
            float dt = softplus_f(z);
            f2 dt2 = {dt, dt};
            f2 e0 = dt2*A2[0], e1 = dt2*A2[1], e2 = dt2*A2[2], e3 = dt2*A2[3];
            f2 a01 = { __expf(e0.x), __expf(e0.y) };
            f2 a23 = { __expf(e1.x), __expf(e1.y) };
            f2 a45 = { __expf(e2.x), __expf(e2.y) };
            f2 a67 = { __expf(e3.x), __expf(e3.y) };

            float dtu = dt*uu;
            f2 du2 = {dtu, dtu};
            f2 Bp0 = { bflo(Bv.x), bfhi(Bv.x) }, Bp1 = { bflo(Bv.y), bfhi(Bv.y) };
            f2 Bp2 = { bflo(Bv.z), bfhi(Bv.z) }, Bp3 = { bflo(Bv.w), bfhi(Bv.w) };
            f2 Cp0 = { bflo(Cv.x), bfhi(Cv.x) }, Cp1 = { bflo(Cv.y), bfhi(Cv.y) };
            f2 Cp2 = { bflo(Cv.z), bfhi(Cv.z) }, Cp3 = { bflo(Cv.w), bfhi(Cv.w) };

            h0  = __builtin_elementwise_fma(a01, h0,  du2*Bp0);
            h1v = __builtin_elementwise_fma(a23, h1v, du2*Bp1);
            h2v = __builtin_elementwise_fma(a45, h2v, du2*Bp2);
            h3  = __builtin_elementwise_fma(a67, h3,  du2*Bp3);

            f2 yv = Cp0*h0;
            yv = __builtin_elementwise_fma(Cp1, h1v, yv);
            yv = __builtin_elementwise_fma(Cp2, h2v, yv);
            yv = __builtin_elementwise_fma(Cp3, h3,  yv);

            float y = yv.x + yv.y + Dd*uu;
            *(u16*)(y4b + yo) = f2bf(y);
            yo += (u32)sy;
        }
    }
}

// ---------------- K5: LN(128) + folded 128->20 + NCHW transpose (pk-FMA) [R6 champion] ----------------
__global__ __launch_bounds__(256) void k_merge(
    const u16* __restrict__ y4, const float* __restrict__ Wt,
    const float* __restrict__ rsum, const float* __restrict__ c0,
    float* __restrict__ out)
{
    __shared__ __align__(16) f2 Wt2_s[128*10];   // [k][o2] = {Wt[k][2o2], Wt[k][2o2+1]}
    __shared__ float rs_s[CIN], c0_s[CIN];
    for (int i = threadIdx.x; i < 128*10; i += 256) {
        int k = i / 10, o2 = i % 10;
        Wt2_s[i] = f2{ Wt[k*CIN + 2*o2], Wt[k*CIN + 2*o2 + 1] };
    }
    if (threadIdx.x < CIN) { rs_s[threadIdx.x] = rsum[threadIdx.x]; c0_s[threadIdx.x] = c0[threadIdx.x]; }
    __syncthreads();

    int p = blockIdx.x*256 + threadIdx.x;
    int b = p / HW, rem = p % HW;

    float s1 = 0.f, s2 = 0.f;
    f2 acc2[10];
    #pragma unroll
    for (int o2 = 0; o2 < 10; ++o2) acc2[o2] = f2{0.f, 0.f};

    #pragma unroll 1
    for (int dirk = 0; dirk < 4; ++dirk) {
        const uint4* src = (const uint4*)(y4 + ((size_t)dirk*BHW + p)*32);
        #pragma unroll
        for (int q4 = 0; q4 < 4; ++q4) {
            uint4 v = src[q4];
            u32 w[4] = {v.x, v.y, v.z, v.w};
            #pragma unroll
            for (int i = 0; i < 4; ++i) {
                int k = dirk*32 + q4*8 + i*2;
                float a = bflo(w[i]); float c = bfhi(w[i]);
                s1 += a + c; s2 += a*a + c*c;
                f2 af = {a, a}, cf = {c, c};
                const float4* w0 = (const float4*)&Wt2_s[k*10];
                const float4* w1 = (const float4*)&Wt2_s[(k+1)*10];
                #pragma unroll
                for (int jq = 0; jq < 5; ++jq) {
                    float4 x0 = w0[jq], x1 = w1[jq];
                    acc2[2*jq]   = __builtin_elementwise_fma(f2{x0.x, x0.y}, af, acc2[2*jq]);
                    acc2[2*jq]   = __builtin_elementwise_fma(f2{x1.x, x1.y}, cf, acc2[2*jq]);
                    acc2[2*jq+1] = __builtin_elementwise_fma(f2{x0.z, x0.w}, af, acc2[2*jq+1]);
                    acc2[2*jq+1] = __builtin_elementwise_fma(f2{x1.z, x1.w}, cf, acc2[2*jq+1]);
                }
            }
        }
    }
    float m = s1*(1.f/128.f);
    float var = s2*(1.f/128.f) - m*m;
    float rstd = rsqrtf(var + EPSF);
    #pragma unroll
    for (int o2 = 0; o2 < 10; ++o2) {
        float r0 = rstd*(acc2[o2].x - m*rs_s[2*o2])   + c0_s[2*o2];
        float r1 = rstd*(acc2[o2].y - m*rs_s[2*o2+1]) + c0_s[2*o2+1];
        out[(b*CIN + 2*o2)*HW + rem]   = r0;
        out[(b*CIN + 2*o2+1)*HW + rem] = r1;
    }
}

extern "C" void kernel_launch(void* const* d_in, const int* in_sizes, int n_in,
                              void* d_out, int out_size, void* d_ws, size_t ws_size,
                              hipStream_t stream)
{
    const float* x    = (const float*)d_in[0];
    const float* ng   = (const float*)d_in[1];
    const float* nb   = (const float*)d_in[2];
    const float* ipw  = (const float*)d_in[3];
    const float* cw   = (const float*)d_in[4];
    const float* cb   = (const float*)d_in[5];
    const float* xw   = (const float*)d_in[6];
    const float* dwm  = (const float*)d_in[7];
    const float* dbv  = (const float*)d_in[8];
    const float* Alog = (const float*)d_in[9];
    const float* Dpv  = (const float*)d_in[10];
    const float* mg   = (const float*)d_in[11];
    const float* mb   = (const float*)d_in[12];
    const float* mw   = (const float*)d_in[13];
    const float* ow   = (const float*)d_in[14];
    const float* ob   = (const float*)d_in[15];
    float* out = (float*)d_out;

    const size_t y4_bytes = (size_t)4*BHW*DIN*2;     // 150,994,944 (planar)
    const size_t dl_bytes = (size_t)4*BHW*8;         //  18,874,368
    const size_t bc_bytes = (size_t)4*BHW*32;        //  75,497,472
    const size_t wt_bytes = (size_t)(128*CIN + 64)*4;

    char* ws = (char*)d_ws;
    u16* y4 = (u16*)ws;

    size_t dl_pos = y4_bytes + GUARD;
    size_t bc_pos = dl_pos + dl_bytes + GUARD;
    size_t wt_pos = bc_pos + bc_bytes + GUARD;
    size_t need   = wt_pos + wt_bytes + GUARD;       // ~245.6 MB (proven budget; ws < 321MB per R4)

    if (ws_size < need) {
        hipMemsetAsync(d_out, 0x7F, (size_t)out_size*4, stream);  // diagnosable sentinel
        return;
    }

    // h2 (u after conv) lives inside d_out with UGUARD front guard (128K for
    // 4-deep prefetch overrun of the vertical-scan u stream: 4*24576 = 96K).
    char* h2base = (char*)d_out;                     // data at +UGUARD
    u16*  h2 = (u16*)(h2base + UGUARD);              // 128K + 37.75MB + 9.3MB tail < 47.19 MB

    u16* dlA = (u16*)(ws + dl_pos);
    u16* bcA = (u16*)(ws + bc_pos);
    float* Wt   = (float*)(ws + wt_pos);
    float* rsum = Wt + 128*CIN;
    float* c0   = rsum + 32;

    k_prep  <<<1, 128, 0, stream>>>(ow, mw, mg, mb, ob, Wt, rsum, c0);
    k_lnconv<<<2304, 256, 0, stream>>>(x, ng, nb, ipw, cw, cb, h2);
    k_proj  <<<BHW/256, 256, 0, stream>>>(h2, xw, dlA, bcA);
    k_scan  <<<768, 256, 0, stream>>>(
        h2base, (const char*)(ws + dl_pos - GUARD), (const char*)(ws + bc_pos - GUARD),
        Alog, Dpv, dwm, dbv, (char*)y4);
    k_merge <<<BHW/256, 256, 0, stream>>>(y4, Wt, rsum, c0, out);
}

// Round 14
// 479.753 us; speedup vs baseline: 1.5950x; 1.0109x over previous
//
#include <hip/hip_runtime.h>

typedef unsigned short u16;
typedef unsigned int   u32;
typedef unsigned long long u64;
typedef float f2 __attribute__((ext_vector_type(2)));

#define CIN  20
#define DIN  32
#define BB   4
#define HH   384
#define WW   384
#define HW   147456
#define BHW  589824
#define EPSF 1e-5f
#define GUARD  65536      // streams with <=49152B 4-step overrun
#define UGUARD 131072     // u stream: 4-step overrun 98304 < 128K

__device__ __forceinline__ float bflo(u32 u) {
    union { u32 v; float f; } x; x.v = u << 16; return x.f;
}
__device__ __forceinline__ float bfhi(u32 u) {
    union { u32 v; float f; } x; x.v = u & 0xffff0000u; return x.f;
}
__device__ __forceinline__ float bf2f(u16 h) {
    union { u32 v; float f; } x; x.v = ((u32)h) << 16; return x.f;
}
__device__ __forceinline__ u16 f2bf(float f) {
    union { float f; u32 u; } v; v.f = f;
    u32 u = v.u;
    return (u16)((u + 0x7FFFu + ((u >> 16) & 1u)) >> 16);
}
__device__ __forceinline__ float silu_f(float a) {
    return a / (1.f + __expf(-a));
}
__device__ __forceinline__ float softplus_f(float z) {
    return (z > 15.f) ? z : __logf(1.f + __expf(z));
}

// ---------------- K0: fold merge+out weights ----------------
__global__ void k_prep(const float* __restrict__ ow, const float* __restrict__ mw,
                       const float* __restrict__ mg, const float* __restrict__ mb,
                       const float* __restrict__ ob,
                       float* __restrict__ Wt, float* __restrict__ rsum,
                       float* __restrict__ c0)
{
    __shared__ float mdot[DIN];
    int t = threadIdx.x; // 128 threads
    if (t < DIN) {
        float s = 0.f;
        for (int k = 0; k < 128; ++k) s += mw[t*128 + k] * mb[k];
        mdot[t] = s;
    }
    {
        int k = t;
        for (int o = 0; o < CIN; ++o) {
            float s = 0.f;
            for (int d = 0; d < DIN; ++d) s += ow[o*DIN + d] * mw[d*128 + k];
            Wt[k*CIN + o] = s * mg[k];
        }
    }
    __syncthreads();
    if (t < CIN) {
        float rs = 0.f;
        for (int k = 0; k < 128; ++k) rs += Wt[k*CIN + t];
        rsum[t] = rs;
        float c = ob[t];
        for (int d = 0; d < DIN; ++d) c += ow[t*DIN + d] * mdot[d];
        c0[t] = c;
    }
}

// ---------------- K_LNCONV: fused LN+inproj+silu -> 3x3 dwconv+silu [R11 proven] ----------------
// Phase 1 = TWO STRAIGHT-LINE blocks with __syncthreads() between (324=256+68).
// Any loop around the LN body lets LICM hoist the 320-float wln_s array ->
// 256 VGPR + scratch spill (R9/R10; "#pragma unroll 1" did NOT stop it).
#define TS   16
#define HT   18
#define CPAD 36
__global__ __launch_bounds__(256) void k_lnconv(
    const float* __restrict__ x, const float* __restrict__ ng,
    const float* __restrict__ nb, const float* __restrict__ ipw,
    const float* __restrict__ cw, const float* __restrict__ cb,
    u16* __restrict__ h2)
{
    __shared__ __align__(16) float hs[HT*HT*CPAD];      // 46656 B
    __shared__ __align__(16) f2 wln_s[CIN*16];          // 2560 B
    __shared__ float g_s[CIN], b_s[CIN];
    __shared__ __align__(16) f2 wc_s[9*16];             // 1152 B
    __shared__ __align__(16) f2 bc2_s[16];

    int tid = threadIdx.x;
    for (int i = tid; i < CIN*16; i += 256) {
        int c = i >> 4, j2 = i & 15;
        wln_s[i] = f2{ ipw[(2*j2)*CIN + c], ipw[(2*j2+1)*CIN + c] };
    }
    if (tid < CIN) { g_s[tid] = ng[tid]; b_s[tid] = nb[tid]; }
    if (tid < 144) wc_s[tid] = f2{ cw[2*tid], cw[2*tid+1] };
    if (tid >= 144 && tid < 160) {
        int i = tid - 144;
        bc2_s[i] = f2{ cb[2*i], cb[2*i+1] };
    }
    __syncthreads();

    int bx = blockIdx.x;
    int b  = bx / 576, t6 = bx % 576;
    int ty0 = (t6 / 24)*TS, tx0 = (t6 % 24)*TS;

    auto do_pixel = [&](int j) {
        int hy = j / HT, hx = j % HT;
        int gy = ty0 + hy - 1, gx = tx0 + hx - 1;
        float* hp = &hs[(hy*HT + hx)*CPAD];
        if (gy >= 0 && gy < HH && gx >= 0 && gx < WW) {
            int rem = gy*WW + gx;
            float v[CIN];
            float m = 0.f;
            #pragma unroll
            for (int c = 0; c < CIN; ++c) { v[c] = x[(b*CIN + c)*HW + rem]; m += v[c]; }
            m *= (1.f/CIN);
            float var = 0.f;
            #pragma unroll
            for (int c = 0; c < CIN; ++c) { float d = v[c]-m; var += d*d; }
            var *= (1.f/CIN);
            float rstd = rsqrtf(var + EPSF);
            #pragma unroll
            for (int c = 0; c < CIN; ++c) v[c] = (v[c]-m)*rstd*g_s[c] + b_s[c];

            f2 o2[16];
            #pragma unroll
            for (int j2 = 0; j2 < 16; ++j2) o2[j2] = f2{0.f, 0.f};
            #pragma unroll
            for (int c = 0; c < CIN; ++c) {
                f2 vc = { v[c], v[c] };
                const float4* wr = (const float4*)&wln_s[c*16];
                #pragma unroll
                for (int jq = 0; jq < 8; ++jq) {
                    float4 wp = wr[jq];
                    o2[2*jq]   = __builtin_elementwise_fma(f2{wp.x, wp.y}, vc, o2[2*jq]);
                    o2[2*jq+1] = __builtin_elementwise_fma(f2{wp.z, wp.w}, vc, o2[2*jq+1]);
                }
            }
            #pragma unroll
            for (int q = 0; q < 8; ++q) {
                float a0 = silu_f(o2[2*q].x),   a1 = silu_f(o2[2*q].y);
                float a2 = silu_f(o2[2*q+1].x), a3 = silu_f(o2[2*q+1].y);
                *(float4*)&hp[4*q] = make_float4(a0, a1, a2, a3);
            }
        } else {
            #pragma unroll
            for (int q = 0; q < 8; ++q)
                *(float4*)&hp[4*q] = make_float4(0.f, 0.f, 0.f, 0.f);
        }
    };

    // ---- phase 1a: halo pixels 0..255 ----
    do_pixel(tid);
    __syncthreads();
    // ---- phase 1b: halo pixels 256..323 ----
    if (tid < HT*HT - 256) do_pixel(256 + tid);
    __syncthreads();

    // ---- phase 2: conv + silu -> h2 ----
    int ty = tid >> 4, tx = tid & 15;
    int gy = ty0 + ty, gx = tx0 + tx;
    int p  = b*HW + gy*WW + gx;

    f2 acc2[16];
    #pragma unroll
    for (int i = 0; i < 16; ++i) acc2[i] = bc2_s[i];

    #pragma unroll
    for (int k = 0; k < 9; ++k) {
        int dy = k/3, dx = k%3;
        const float* np = &hs[((ty+dy)*HT + (tx+dx))*CPAD];
        const f2* wk = &wc_s[k*16];
        #pragma unroll
        for (int q = 0; q < 8; ++q) {
            float4 t4 = *(const float4*)&np[4*q];
            acc2[2*q]   = __builtin_elementwise_fma(wk[2*q],   f2{t4.x, t4.y}, acc2[2*q]);
            acc2[2*q+1] = __builtin_elementwise_fma(wk[2*q+1], f2{t4.z, t4.w}, acc2[2*q+1]);
        }
    }

    u32 pk[16];
    #pragma unroll
    for (int i = 0; i < 16; ++i) {
        float a = silu_f(acc2[i].x);
        float c = silu_f(acc2[i].y);
        pk[i] = (u32)f2bf(a) | ((u32)f2bf(c) << 16);
    }
    uint4* dst = (uint4*)(h2 + (size_t)p*DIN);
    dst[0] = make_uint4(pk[0],pk[1],pk[2],pk[3]);
    dst[1] = make_uint4(pk[4],pk[5],pk[6],pk[7]);
    dst[2] = make_uint4(pk[8],pk[9],pk[10],pk[11]);
    dst[3] = make_uint4(pk[12],pk[13],pk[14],pk[15]);
}

// ---------------- K3: xdbl -> dl + BC, pk-FMA, 2-pixel register blocking ----------------
// Each thread handles pixels (p, p+1): the 320 wave-uniform weight ds_read_b128
// per pixel are SHARED by both pixels (640 -> 320 per 2 pixels) — the LDS read
// pipe is the non-scan bottleneck (~8cyc/wave per b128, 36 waves/CU).
// Per-pixel accumulation order identical to R6 (bit-exact).
__global__ __launch_bounds__(256) void k_proj(
    const u16* __restrict__ h2, const float* __restrict__ xw,
    u16* __restrict__ dlA, u16* __restrict__ bcA)
{
    __shared__ __align__(16) f2 xw2_s[4*DIN*10];
    for (int i = threadIdx.x; i < 4*DIN*10; i += 256) {
        int dir = i / 320, r = i % 320;
        int d = r / 10, j2 = r % 10;
        xw2_s[i] = f2{ xw[(dir*CIN + 2*j2)*DIN + d],
                       xw[(dir*CIN + 2*j2 + 1)*DIN + d] };
    }
    __syncthreads();

    int p = (blockIdx.x*256 + threadIdx.x)*2;
    float ua[DIN], ub[DIN];
    const uint4* src = (const uint4*)(h2 + (size_t)p*DIN);
    #pragma unroll
    for (int q4 = 0; q4 < 4; ++q4) {
        uint4 v = src[q4];
        ua[q4*8+0]=bflo(v.x); ua[q4*8+1]=bfhi(v.x);
        ua[q4*8+2]=bflo(v.y); ua[q4*8+3]=bfhi(v.y);
        ua[q4*8+4]=bflo(v.z); ua[q4*8+5]=bfhi(v.z);
        ua[q4*8+6]=bflo(v.w); ua[q4*8+7]=bfhi(v.w);
        uint4 w = src[q4+4];
        ub[q4*8+0]=bflo(w.x); ub[q4*8+1]=bfhi(w.x);
        ub[q4*8+2]=bflo(w.y); ub[q4*8+3]=bfhi(w.y);
        ub[q4*8+4]=bflo(w.z); ub[q4*8+5]=bfhi(w.z);
        ub[q4*8+6]=bflo(w.w); ub[q4*8+7]=bfhi(w.w);
    }
    #pragma unroll 1
    for (int dir = 0; dir < 4; ++dir) {
        f2 xa[10], xb[10];
        #pragma unroll
        for (int j2 = 0; j2 < 10; ++j2) { xa[j2] = f2{0.f,0.f}; xb[j2] = f2{0.f,0.f}; }
        #pragma unroll
        for (int d = 0; d < DIN; ++d) {
            f2 uda = { ua[d], ua[d] };
            f2 udb = { ub[d], ub[d] };
            const float4* wr = (const float4*)&xw2_s[(dir*DIN + d)*10];
            #pragma unroll
            for (int jq = 0; jq < 5; ++jq) {
                float4 wp = wr[jq];
                f2 wlo = {wp.x, wp.y}, whi = {wp.z, wp.w};
                xa[2*jq]   = __builtin_elementwise_fma(wlo, uda, xa[2*jq]);
                xa[2*jq+1] = __builtin_elementwise_fma(whi, uda, xa[2*jq+1]);
                xb[2*jq]   = __builtin_elementwise_fma(wlo, udb, xb[2*jq]);
                xb[2*jq+1] = __builtin_elementwise_fma(whi, udb, xb[2*jq+1]);
            }
        }
        u32 pa[10], pb[10];
        #pragma unroll
        for (int i = 0; i < 10; ++i) {
            pa[i] = (u32)f2bf(xa[i].x) | ((u32)f2bf(xa[i].y) << 16);
            pb[i] = (u32)f2bf(xb[i].x) | ((u32)f2bf(xb[i].y) << 16);
        }
        // dl: two adjacent 8B records -> one uint4 (16B aligned: p even)
        *(uint4*)(dlA + (size_t)(dir*BHW + p)*4) = make_uint4(pa[0], pa[1], pb[0], pb[1]);
        // bc: two adjacent 32B records -> four uint4
        uint4* bcd = (uint4*)(bcA + (size_t)(dir*BHW + p)*16);
        bcd[0] = make_uint4(pa[2], pa[3], pa[4], pa[5]);   // A: B0..B7
        bcd[1] = make_uint4(pa[6], pa[7], pa[8], pa[9]);   // A: C0..C7
        bcd[2] = make_uint4(pb[2], pb[3], pb[4], pb[5]);   // B: B0..B7
        bcd[3] = make_uint4(pb[6], pb[7], pb[8], pb[9]);   // B: C0..C7
    }
}

// ---------------- K4: 4-direction selective scan [R2/R6 champion, unchanged] ----------------
__global__ __launch_bounds__(256) void k_scan(
    const char* __restrict__ h2b,   // u data at +UGUARD
    const char* __restrict__ dlb_,  // dl data at +GUARD (8B records)
    const char* __restrict__ bcb_,  // (B,C) data at +GUARD (32B records)
    const float* __restrict__ Alog, const float* __restrict__ Dp,
    const float* __restrict__ dwm,  const float* __restrict__ dbv,
    char* __restrict__ y4b)         // planar (dir, pixel, 32) bf16
{
    int tid  = blockIdx.x*256 + threadIdx.x;
    int wv   = tid >> 6, lane = tid & 63;
    int half = lane >> 5, d = lane & 31;
    int dir  = wv / 768;                 // uniform per wave
    int s    = (wv % 768)*2 + half;
    int b    = s / 384, r = s % 384;

    int p0, stp;
    if (dir == 0)      { p0 = b*HW + r*WW;           stp = 1;  }
    else if (dir == 1) { p0 = b*HW + r*WW + (WW-1);  stp = -1; }
    else if (dir == 2) { p0 = b*HW + r;              stp = WW; }
    else               { p0 = b*HW + (HH-1)*WW + r;  stp = -WW;}

    float Av[8];
    bool okl = true;
    #pragma unroll
    for (int j = 0; j < 8; ++j) {
        float e = __expf(Alog[(dir*DIN + d)*8 + j]);
        Av[j] = -e;
        okl = okl && (__builtin_fabsf(e - (float)(j+1)) < 2e-3f);
    }
    bool fast = (__ballot(okl) == ~0ull);

    float Dd  = Dp[dir*DIN + d];
    float dw0 = dwm[(dir*DIN + d)*4 + 0], dw1 = dwm[(dir*DIN + d)*4 + 1];
    float dw2 = dwm[(dir*DIN + d)*4 + 2], dw3 = dwm[(dir*DIN + d)*4 + 3];
    float dbc = dbv[dir*DIN + d];

    u32 uo = UGUARD + (u32)((p0*DIN + d)*2);           int su = stp*DIN*2;
    u32 yo = (u32)((dir*BHW + p0)*64 + d*2);           int sy = stp*64;
    u32 c1 = GUARD + (u32)((dir*BHW + p0)*8);          int s1 = stp*8;
    u32 c2 = GUARD + (u32)((dir*BHW + p0)*32);         int s2 = stp*32;

    u16 ub[4]; uint2 dlr[4]; uint4 B4[4], C4[4];
    u32 fu = uo, f1 = c1, f2o = c2;

    auto fetch = [&](int sl) {
        ub[sl]  = *(const u16*)(h2b + fu);
        dlr[sl] = *(const uint2*)(dlb_ + f1);
        B4[sl]  = *(const uint4*)(bcb_ + f2o);
        C4[sl]  = *(const uint4*)(bcb_ + f2o + 16);
        fu += (u32)su; f1 += (u32)s1; f2o += (u32)s2;
    };

    #pragma unroll
    for (int i = 0; i < 4; ++i) fetch(i);

    f2 h0 = {0.f,0.f}, h1v = {0.f,0.f}, h2v = {0.f,0.f}, h3 = {0.f,0.f};

    if (fast) {
        f2 a01, a23, a45, a67;
        f2 Bq0, Bq1, Bq2, Bq3;
        f2 Cp0, Cp1, Cp2, Cp3;
        float ydc;

        auto prep = [&](int sl) {
            float uu = bf2f(ub[sl]);
            uint2 dl = dlr[sl];
            uint4 Bv = B4[sl], Cv = C4[sl];
            float z = dbc + dw0*bflo(dl.x) + dw1*bfhi(dl.x)
                          + dw2*bflo(dl.y) + dw3*bfhi(dl.y);
            z = fminf(z, 80.f);
            float ez = __expf(z);
            float w  = 1.f + ez;
            float rr = __builtin_amdgcn_rcpf(w);   // = exp(-dt)
            float dt = __logf(w);                  // softplus(z); parallel with rcp
            float r2 = rr*rr;
            f2 rr2 = {r2, r2};
            f2 t01 = {rr, r2};
            a01 = t01;
            a23 = t01*rr2;
            a45 = a23*rr2;
            a67 = a45*rr2;
            float dtu = dt*uu;
            f2 du2 = {dtu, dtu};
            f2 Bp0 = { bflo(Bv.x), bfhi(Bv.x) }, Bp1 = { bflo(Bv.y), bfhi(Bv.y) };
            f2 Bp2 = { bflo(Bv.z), bfhi(Bv.z) }, Bp3 = { bflo(Bv.w), bfhi(Bv.w) };
            Bq0 = du2*Bp0; Bq1 = du2*Bp1; Bq2 = du2*Bp2; Bq3 = du2*Bp3;
            f2 c0 = { bflo(Cv.x), bfhi(Cv.x) }, c1v = { bflo(Cv.y), bfhi(Cv.y) };
            f2 c2v = { bflo(Cv.z), bfhi(Cv.z) }, c3 = { bflo(Cv.w), bfhi(Cv.w) };
            Cp0 = c0; Cp1 = c1v; Cp2 = c2v; Cp3 = c3;
            ydc = Dd*uu;
        };

        prep(0);

        #pragma unroll 4
        for (int t = 0; t < 384; ++t) {
            int sl = t & 3;
            fetch(sl);

            h0  = __builtin_elementwise_fma(a01, h0,  Bq0);
            h1v = __builtin_elementwise_fma(a23, h1v, Bq1);
            h2v = __builtin_elementwise_fma(a45, h2v, Bq2);
            h3  = __builtin_elementwise_fma(a67, h3,  Bq3);

            f2 yv = Cp0*h0;
            yv = __builtin_elementwise_fma(Cp1, h1v, yv);
            yv = __builtin_elementwise_fma(Cp2, h2v, yv);
            yv = __builtin_elementwise_fma(Cp3, h3,  yv);
            float y = yv.x + yv.y + ydc;

            prep((t+1) & 3);

            *(u16*)(y4b + yo) = f2bf(y);
            yo += (u32)sy;
        }
    } else {
        f2 A2[4];
        #pragma unroll
        for (int j = 0; j < 4; ++j) { A2[j].x = Av[2*j]; A2[j].y = Av[2*j+1]; }
        #pragma unroll 4
        for (int t = 0; t < 384; ++t) {
            int sl = t & 3;
            float uu = bf2f(ub[sl]);
            uint2 dl = dlr[sl];
            uint4 Bv = B4[sl], Cv = C4[sl];
            fetch(sl);

            float z = dbc + dw0*bflo(dl.x) + dw1*bfhi(dl.x)
                          + dw2*bflo(dl.y) + dw3*bfhi(dl.y);
            float dt = softplus_f(z);
            f2 dt2 = {dt, dt};
            f2 e0 = dt2*A2[0], e1 = dt2*A2[1], e2 = dt2*A2[2], e3 = dt2*A2[3];
            f2 a01 = { __expf(e0.x), __expf(e0.y) };
            f2 a23 = { __expf(e1.x), __expf(e1.y) };
            f2 a45 = { __expf(e2.x), __expf(e2.y) };
            f2 a67 = { __expf(e3.x), __expf(e3.y) };

            float dtu = dt*uu;
            f2 du2 = {dtu, dtu};
            f2 Bp0 = { bflo(Bv.x), bfhi(Bv.x) }, Bp1 = { bflo(Bv.y), bfhi(Bv.y) };
            f2 Bp2 = { bflo(Bv.z), bfhi(Bv.z) }, Bp3 = { bflo(Bv.w), bfhi(Bv.w) };
            f2 Cp0 = { bflo(Cv.x), bfhi(Cv.x) }, Cp1 = { bflo(Cv.y), bfhi(Cv.y) };
            f2 Cp2 = { bflo(Cv.z), bfhi(Cv.z) }, Cp3 = { bflo(Cv.w), bfhi(Cv.w) };

            h0  = __builtin_elementwise_fma(a01, h0,  du2*Bp0);
            h1v = __builtin_elementwise_fma(a23, h1v, du2*Bp1);
            h2v = __builtin_elementwise_fma(a45, h2v, du2*Bp2);
            h3  = __builtin_elementwise_fma(a67, h3,  du2*Bp3);

            f2 yv = Cp0*h0;
            yv = __builtin_elementwise_fma(Cp1, h1v, yv);
            yv = __builtin_elementwise_fma(Cp2, h2v, yv);
            yv = __builtin_elementwise_fma(Cp3, h3,  yv);

            float y = yv.x + yv.y + Dd*uu;
            *(u16*)(y4b + yo) = f2bf(y);
            yo += (u32)sy;
        }
    }
}

// ---------------- K5: LN(128) + folded 128->20 + transpose, 2-pixel blocking ----------------
// Each thread handles pixels (p, p+1): the 320 uniform Wt ds_read_b128 per
// pixel are shared (640 -> 320 per 2 pixels). Per-pixel accumulation order
// identical to R6. out written as float2 (rem even; pair never straddles b).
__global__ __launch_bounds__(256) void k_merge(
    const u16* __restrict__ y4, const float* __restrict__ Wt,
    const float* __restrict__ rsum, const float* __restrict__ c0,
    float* __restrict__ out)
{
    __shared__ __align__(16) f2 Wt2_s[128*10];   // [k][o2] = {Wt[k][2o2], Wt[k][2o2+1]}
    __shared__ float rs_s[CIN], c0_s[CIN];
    for (int i = threadIdx.x; i < 128*10; i += 256) {
        int k = i / 10, o2 = i % 10;
        Wt2_s[i] = f2{ Wt[k*CIN + 2*o2], Wt[k*CIN + 2*o2 + 1] };
    }
    if (threadIdx.x < CIN) { rs_s[threadIdx.x] = rsum[threadIdx.x]; c0_s[threadIdx.x] = c0[threadIdx.x]; }
    __syncthreads();

    int p = (blockIdx.x*256 + threadIdx.x)*2;
    int b = p / HW, rem = p % HW;    // p even, HW even: pair never straddles b

    float s1a = 0.f, s2a = 0.f, s1b = 0.f, s2b = 0.f;
    f2 acca[10], accb[10];
    #pragma unroll
    for (int o2 = 0; o2 < 10; ++o2) { acca[o2] = f2{0.f,0.f}; accb[o2] = f2{0.f,0.f}; }

    #pragma unroll 1
    for (int dirk = 0; dirk < 4; ++dirk) {
        const uint4* src = (const uint4*)(y4 + ((size_t)dirk*BHW + p)*32);
        #pragma unroll
        for (int q4 = 0; q4 < 4; ++q4) {
            uint4 va = src[q4];
            uint4 vb = src[q4+4];
            u32 wa[4] = {va.x, va.y, va.z, va.w};
            u32 wb[4] = {vb.x, vb.y, vb.z, vb.w};
            #pragma unroll
            for (int i = 0; i < 4; ++i) {
                int k = dirk*32 + q4*8 + i*2;
                float aa = bflo(wa[i]); float ca = bfhi(wa[i]);
                float ab = bflo(wb[i]); float cb = bfhi(wb[i]);
                s1a += aa + ca; s2a += aa*aa + ca*ca;
                s1b += ab + cb; s2b += ab*ab + cb*cb;
                f2 afa = {aa, aa}, cfa = {ca, ca};
                f2 afb = {ab, ab}, cfb = {cb, cb};
                const float4* w0 = (const float4*)&Wt2_s[k*10];
                const float4* w1 = (const float4*)&Wt2_s[(k+1)*10];
                #pragma unroll
                for (int jq = 0; jq < 5; ++jq) {
                    float4 x0 = w0[jq], x1 = w1[jq];
                    f2 x0lo = {x0.x, x0.y}, x0hi = {x0.z, x0.w};
                    f2 x1lo = {x1.x, x1.y}, x1hi = {x1.z, x1.w};
                    acca[2*jq]   = __builtin_elementwise_fma(x0lo, afa, acca[2*jq]);
                    acca[2*jq]   = __builtin_elementwise_fma(x1lo, cfa, acca[2*jq]);
                    acca[2*jq+1] = __builtin_elementwise_fma(x0hi, afa, acca[2*jq+1]);
                    acca[2*jq+1] = __builtin_elementwise_fma(x1hi, cfa, acca[2*jq+1]);
                    accb[2*jq]   = __builtin_elementwise_fma(x0lo, afb, accb[2*jq]);
                    accb[2*jq]   = __builtin_elementwise_fma(x1lo, cfb, accb[2*jq]);
                    accb[2*jq+1] = __builtin_elementwise_fma(x0hi, afb, accb[2*jq+1]);
                    accb[2*jq+1] = __builtin_elementwise_fma(x1hi, cfb, accb[2*jq+1]);
                }
            }
        }
    }
    float ma = s1a*(1.f/128.f);
    float va = s2a*(1.f/128.f) - ma*ma;
    float ra = rsqrtf(va + EPSF);
    float mb2 = s1b*(1.f/128.f);
    float vb2 = s2b*(1.f/128.f) - mb2*mb2;
    float rb = rsqrtf(vb2 + EPSF);
    #pragma unroll
    for (int o2 = 0; o2 < 10; ++o2) {
        float a0 = ra*(acca[o2].x - ma*rs_s[2*o2])    + c0_s[2*o2];
        float a1 = ra*(acca[o2].y - ma*rs_s[2*o2+1])  + c0_s[2*o2+1];
        float b0 = rb*(accb[o2].x - mb2*rs_s[2*o2])   + c0_s[2*o2];
        float b1 = rb*(accb[o2].y - mb2*rs_s[2*o2+1]) + c0_s[2*o2+1];
        *(float2*)&out[(b*CIN + 2*o2)*HW + rem]   = float2{a0, b0};
        *(float2*)&out[(b*CIN + 2*o2+1)*HW + rem] = float2{a1, b1};
    }
}

extern "C" void kernel_launch(void* const* d_in, const int* in_sizes, int n_in,
                              void* d_out, int out_size, void* d_ws, size_t ws_size,
                              hipStream_t stream)
{
    const float* x    = (const float*)d_in[0];
    const float* ng   = (const float*)d_in[1];
    const float* nb   = (const float*)d_in[2];
    const float* ipw  = (const float*)d_in[3];
    const float* cw   = (const float*)d_in[4];
    const float* cb   = (const float*)d_in[5];
    const float* xw   = (const float*)d_in[6];
    const float* dwm  = (const float*)d_in[7];
    const float* dbv  = (const float*)d_in[8];
    const float* Alog = (const float*)d_in[9];
    const float* Dpv  = (const float*)d_in[10];
    const float* mg   = (const float*)d_in[11];
    const float* mb   = (const float*)d_in[12];
    const float* mw   = (const float*)d_in[13];
    const float* ow   = (const float*)d_in[14];
    const float* ob   = (const float*)d_in[15];
    float* out = (float*)d_out;

    const size_t y4_bytes = (size_t)4*BHW*DIN*2;     // 150,994,944 (planar)
    const size_t dl_bytes = (size_t)4*BHW*8;         //  18,874,368
    const size_t bc_bytes = (size_t)4*BHW*32;        //  75,497,472
    const size_t wt_bytes = (size_t)(128*CIN + 64)*4;

    char* ws = (char*)d_ws;
    u16* y4 = (u16*)ws;

    size_t dl_pos = y4_bytes + GUARD;
    size_t bc_pos = dl_pos + dl_bytes + GUARD;
    size_t wt_pos = bc_pos + bc_bytes + GUARD;
    size_t need   = wt_pos + wt_bytes + GUARD;       // ~245.6 MB (proven budget; ws < 321MB per R4)

    if (ws_size < need) {
        hipMemsetAsync(d_out, 0x7F, (size_t)out_size*4, stream);  // diagnosable sentinel
        return;
    }

    // h2 (u after conv) lives inside d_out with UGUARD front guard (128K for
    // 4-deep prefetch overrun of the vertical-scan u stream: 4*24576 = 96K).
    char* h2base = (char*)d_out;                     // data at +UGUARD
    u16*  h2 = (u16*)(h2base + UGUARD);              // 128K + 37.75MB + 9.3MB tail < 47.19 MB

    u16* dlA = (u16*)(ws + dl_pos);
    u16* bcA = (u16*)(ws + bc_pos);
    float* Wt   = (float*)(ws + wt_pos);
    float* rsum = Wt + 128*CIN;
    float* c0   = rsum + 32;

    k_prep  <<<1, 128, 0, stream>>>(ow, mw, mg, mb, ob, Wt, rsum, c0);
    k_lnconv<<<2304, 256, 0, stream>>>(x, ng, nb, ipw, cw, cb, h2);
    k_proj  <<<BHW/512, 256, 0, stream>>>(h2, xw, dlA, bcA);
    k_scan  <<<768, 256, 0, stream>>>(
        h2base, (const char*)(ws + dl_pos - GUARD), (const char*)(ws + bc_pos - GUARD),
        Alog, Dpv, dwm, dbv, (char*)y4);
    k_merge <<<BHW/512, 256, 0, stream>>>(y4, Wt, rsum, c0, out);
}

// Round 15
// 471.018 us; speedup vs baseline: 1.6245x; 1.0185x over previous
//
#include <hip/hip_runtime.h>

typedef unsigned short u16;
typedef unsigned int   u32;
typedef unsigned long long u64;
typedef float f2 __attribute__((ext_vector_type(2)));

#define CIN  20
#define DIN  32
#define BB   4
#define HH   384
#define WW   384
#define HW   147456
#define BHW  589824
#define EPSF 1e-5f
#define GUARD  65536      // streams with <=49152B 4-step overrun
#define UGUARD 131072     // u stream: 4-step overrun 98304 < 128K

__device__ __forceinline__ float bflo(u32 u) {
    union { u32 v; float f; } x; x.v = u << 16; return x.f;
}
__device__ __forceinline__ float bfhi(u32 u) {
    union { u32 v; float f; } x; x.v = u & 0xffff0000u; return x.f;
}
__device__ __forceinline__ float bf2f(u16 h) {
    union { u32 v; float f; } x; x.v = ((u32)h) << 16; return x.f;
}
__device__ __forceinline__ u16 f2bf(float f) {
    union { float f; u32 u; } v; v.f = f;
    u32 u = v.u;
    return (u16)((u + 0x7FFFu + ((u >> 16) & 1u)) >> 16);
}
__device__ __forceinline__ float silu_f(float a) {
    return a / (1.f + __expf(-a));
}
__device__ __forceinline__ float softplus_f(float z) {
    return (z > 15.f) ? z : __logf(1.f + __expf(z));
}

// ---------------- K_FRONT: LN+inproj+silu -> conv+silu -> proj (+prep in block 0) ----------------
// Pipeline restructure (R14 lesson: non-scan internals don't move total; fixed
// serial/launch costs do). 5 launches -> 3. Phases (barrier-separated to keep
// register lifetimes apart — the R11 anti-spill discipline; NO loops around
// the LN body, R9/R10 LICM evidence):
//   1a/1b: LN+inproj+silu for 18x18 halo -> LDS hs (straight-line x2)
//   2:     3x3 conv from hs + silu -> u[32] f32 in REGISTERS; h2 bf16 store
//   (bar)  xw2 OVERLAYS the dead hs storage (keeps LDS ~51KB -> 3 blocks/CU)
//   3:     proj from register u (verbatim R6 body) -> dl + bc
//   block0 only: k_prep folded in (hidden under other blocks' work)
#define TS   16
#define HT   18
#define CPAD 36
__global__ __launch_bounds__(256) void k_front(
    const float* __restrict__ x, const float* __restrict__ ng,
    const float* __restrict__ nb, const float* __restrict__ ipw,
    const float* __restrict__ cw, const float* __restrict__ cb,
    const float* __restrict__ xw,
    const float* __restrict__ ow, const float* __restrict__ mw,
    const float* __restrict__ mg, const float* __restrict__ mb,
    const float* __restrict__ ob,
    u16* __restrict__ h2, u16* __restrict__ dlA, u16* __restrict__ bcA,
    float* __restrict__ Wt, float* __restrict__ rsum, float* __restrict__ c0)
{
    __shared__ __align__(16) float sraw[HT*HT*CPAD];    // 46656 B: hs, later xw2 overlay
    __shared__ __align__(16) f2 wln_s[CIN*16];          // 2560 B
    __shared__ float g_s[CIN], b_s[CIN];
    __shared__ __align__(16) f2 wc_s[9*16];             // 1152 B
    __shared__ __align__(16) f2 bc2_s[16];
    __shared__ float mdot[DIN];

    float* hs = sraw;
    f2* xw2_s = (f2*)sraw;                              // valid after phase-2 barrier

    int tid = threadIdx.x;
    for (int i = tid; i < CIN*16; i += 256) {
        int c = i >> 4, j2 = i & 15;
        wln_s[i] = f2{ ipw[(2*j2)*CIN + c], ipw[(2*j2+1)*CIN + c] };
    }
    if (tid < CIN) { g_s[tid] = ng[tid]; b_s[tid] = nb[tid]; }
    if (tid < 144) wc_s[tid] = f2{ cw[2*tid], cw[2*tid+1] };
    if (tid >= 144 && tid < 160) {
        int i = tid - 144;
        bc2_s[i] = f2{ cb[2*i], cb[2*i+1] };
    }
    __syncthreads();

    int bx = blockIdx.x;
    int b  = bx / 576, t6 = bx % 576;
    int ty0 = (t6 / 24)*TS, tx0 = (t6 % 24)*TS;

    auto do_pixel = [&](int j) {
        int hy = j / HT, hx = j % HT;
        int gy = ty0 + hy - 1, gx = tx0 + hx - 1;
        float* hp = &hs[(hy*HT + hx)*CPAD];
        if (gy >= 0 && gy < HH && gx >= 0 && gx < WW) {
            int rem = gy*WW + gx;
            float v[CIN];
            float m = 0.f;
            #pragma unroll
            for (int c = 0; c < CIN; ++c) { v[c] = x[(b*CIN + c)*HW + rem]; m += v[c]; }
            m *= (1.f/CIN);
            float var = 0.f;
            #pragma unroll
            for (int c = 0; c < CIN; ++c) { float d = v[c]-m; var += d*d; }
            var *= (1.f/CIN);
            float rstd = rsqrtf(var + EPSF);
            #pragma unroll
            for (int c = 0; c < CIN; ++c) v[c] = (v[c]-m)*rstd*g_s[c] + b_s[c];

            f2 o2[16];
            #pragma unroll
            for (int j2 = 0; j2 < 16; ++j2) o2[j2] = f2{0.f, 0.f};
            #pragma unroll
            for (int c = 0; c < CIN; ++c) {
                f2 vc = { v[c], v[c] };
                const float4* wr = (const float4*)&wln_s[c*16];
                #pragma unroll
                for (int jq = 0; jq < 8; ++jq) {
                    float4 wp = wr[jq];
                    o2[2*jq]   = __builtin_elementwise_fma(f2{wp.x, wp.y}, vc, o2[2*jq]);
                    o2[2*jq+1] = __builtin_elementwise_fma(f2{wp.z, wp.w}, vc, o2[2*jq+1]);
                }
            }
            #pragma unroll
            for (int q = 0; q < 8; ++q) {
                float a0 = silu_f(o2[2*q].x),   a1 = silu_f(o2[2*q].y);
                float a2 = silu_f(o2[2*q+1].x), a3 = silu_f(o2[2*q+1].y);
                *(float4*)&hp[4*q] = make_float4(a0, a1, a2, a3);
            }
        } else {
            #pragma unroll
            for (int q = 0; q < 8; ++q)
                *(float4*)&hp[4*q] = make_float4(0.f, 0.f, 0.f, 0.f);
        }
    };

    // ---- phase 1a: halo pixels 0..255 (straight-line) ----
    do_pixel(tid);
    __syncthreads();
    // ---- phase 1b: halo pixels 256..323 ----
    if (tid < HT*HT - 256) do_pixel(256 + tid);
    __syncthreads();

    // ---- phase 2: conv + silu -> u[32] in registers; h2 store ----
    int ty = tid >> 4, tx = tid & 15;
    int gy = ty0 + ty, gx = tx0 + tx;
    int p  = b*HW + gy*WW + gx;

    f2 acc2[16];
    #pragma unroll
    for (int i = 0; i < 16; ++i) acc2[i] = bc2_s[i];

    #pragma unroll
    for (int k = 0; k < 9; ++k) {
        int dy = k/3, dx = k%3;
        const float* np = &hs[((ty+dy)*HT + (tx+dx))*CPAD];
        const f2* wk = &wc_s[k*16];
        #pragma unroll
        for (int q = 0; q < 8; ++q) {
            float4 t4 = *(const float4*)&np[4*q];
            acc2[2*q]   = __builtin_elementwise_fma(wk[2*q],   f2{t4.x, t4.y}, acc2[2*q]);
            acc2[2*q+1] = __builtin_elementwise_fma(wk[2*q+1], f2{t4.z, t4.w}, acc2[2*q+1]);
        }
    }

    float u[DIN];
    #pragma unroll
    for (int i = 0; i < 16; ++i) {
        u[2*i]   = silu_f(acc2[i].x);
        u[2*i+1] = silu_f(acc2[i].y);
    }
    {
        u32 pk[16];
        #pragma unroll
        for (int i = 0; i < 16; ++i)
            pk[i] = (u32)f2bf(u[2*i]) | ((u32)f2bf(u[2*i+1]) << 16);
        uint4* dst = (uint4*)(h2 + (size_t)p*DIN);
        dst[0] = make_uint4(pk[0],pk[1],pk[2],pk[3]);
        dst[1] = make_uint4(pk[4],pk[5],pk[6],pk[7]);
        dst[2] = make_uint4(pk[8],pk[9],pk[10],pk[11]);
        dst[3] = make_uint4(pk[12],pk[13],pk[14],pk[15]);
    }
    __syncthreads();   // all hs reads complete -> overlay is safe

    // ---- xw2 overlay fill (onto dead hs storage) ----
    for (int i = tid; i < 4*DIN*10; i += 256) {
        int dir = i / 320, r = i % 320;
        int d = r / 10, j2 = r % 10;
        xw2_s[i] = f2{ xw[(dir*CIN + 2*j2)*DIN + d],
                       xw[(dir*CIN + 2*j2 + 1)*DIN + d] };
    }
    __syncthreads();

    // ---- phase 3: proj from register u (verbatim R6 body) ----
    #pragma unroll 1
    for (int dir = 0; dir < 4; ++dir) {
        f2 xd2[10];
        #pragma unroll
        for (int j2 = 0; j2 < 10; ++j2) xd2[j2] = f2{0.f, 0.f};
        #pragma unroll
        for (int d = 0; d < DIN; ++d) {
            f2 ud = { u[d], u[d] };
            const float4* wr = (const float4*)&xw2_s[(dir*DIN + d)*10];
            #pragma unroll
            for (int jq = 0; jq < 5; ++jq) {
                float4 wp = wr[jq];
                xd2[2*jq]   = __builtin_elementwise_fma(f2{wp.x, wp.y}, ud, xd2[2*jq]);
                xd2[2*jq+1] = __builtin_elementwise_fma(f2{wp.z, wp.w}, ud, xd2[2*jq+1]);
            }
        }
        u32 pk[10];
        #pragma unroll
        for (int i = 0; i < 10; ++i)
            pk[i] = (u32)f2bf(xd2[i].x) | ((u32)f2bf(xd2[i].y) << 16);
        *(uint2*)(dlA + (size_t)(dir*BHW + p)*4) = make_uint2(pk[0], pk[1]);
        uint4* bcd = (uint4*)(bcA + (size_t)(dir*BHW + p)*16);
        bcd[0] = make_uint4(pk[2], pk[3], pk[4], pk[5]);   // B0..B7
        bcd[1] = make_uint4(pk[6], pk[7], pk[8], pk[9]);   // C0..C7
    }

    // ---- k_prep folded into block 0 (hidden under the other 2303 blocks) ----
    if (bx == 0) {
        int t = tid;
        if (t < DIN) {
            float s = 0.f;
            for (int k = 0; k < 128; ++k) s += mw[t*128 + k] * mb[k];
            mdot[t] = s;
        }
        if (t < 128) {
            int k = t;
            for (int o = 0; o < CIN; ++o) {
                float s = 0.f;
                for (int d = 0; d < DIN; ++d) s += ow[o*DIN + d] * mw[d*128 + k];
                Wt[k*CIN + o] = s * mg[k];
            }
        }
        __syncthreads();
        if (t < CIN) {
            float rs = 0.f;
            for (int k = 0; k < 128; ++k) rs += Wt[k*CIN + t];
            rsum[t] = rs;
            float c = ob[t];
            for (int d = 0; d < DIN; ++d) c += ow[t*DIN + d] * mdot[d];
            c0[t] = c;
        }
    }
}

// ---------------- K4: 4-direction selective scan [R2/R6 champion, unchanged] ----------------
__global__ __launch_bounds__(256) void k_scan(
    const char* __restrict__ h2b,   // u data at +UGUARD
    const char* __restrict__ dlb_,  // dl data at +GUARD (8B records)
    const char* __restrict__ bcb_,  // (B,C) data at +GUARD (32B records)
    const float* __restrict__ Alog, const float* __restrict__ Dp,
    const float* __restrict__ dwm,  const float* __restrict__ dbv,
    char* __restrict__ y4b)         // planar (dir, pixel, 32) bf16
{
    int tid  = blockIdx.x*256 + threadIdx.x;
    int wv   = tid >> 6, lane = tid & 63;
    int half = lane >> 5, d = lane & 31;
    int dir  = wv / 768;                 // uniform per wave
    int s    = (wv % 768)*2 + half;
    int b    = s / 384, r = s % 384;

    int p0, stp;
    if (dir == 0)      { p0 = b*HW + r*WW;           stp = 1;  }
    else if (dir == 1) { p0 = b*HW + r*WW + (WW-1);  stp = -1; }
    else if (dir == 2) { p0 = b*HW + r;              stp = WW; }
    else               { p0 = b*HW + (HH-1)*WW + r;  stp = -WW;}

    float Av[8];
    bool okl = true;
    #pragma unroll
    for (int j = 0; j < 8; ++j) {
        float e = __expf(Alog[(dir*DIN + d)*8 + j]);
        Av[j] = -e;
        okl = okl && (__builtin_fabsf(e - (float)(j+1)) < 2e-3f);
    }
    bool fast = (__ballot(okl) == ~0ull);

    float Dd  = Dp[dir*DIN + d];
    float dw0 = dwm[(dir*DIN + d)*4 + 0], dw1 = dwm[(dir*DIN + d)*4 + 1];
    float dw2 = dwm[(dir*DIN + d)*4 + 2], dw3 = dwm[(dir*DIN + d)*4 + 3];
    float dbc = dbv[dir*DIN + d];

    u32 uo = UGUARD + (u32)((p0*DIN + d)*2);           int su = stp*DIN*2;
    u32 yo = (u32)((dir*BHW + p0)*64 + d*2);           int sy = stp*64;
    u32 c1 = GUARD + (u32)((dir*BHW + p0)*8);          int s1 = stp*8;
    u32 c2 = GUARD + (u32)((dir*BHW + p0)*32);         int s2 = stp*32;

    u16 ub[4]; uint2 dlr[4]; uint4 B4[4], C4[4];
    u32 fu = uo, f1 = c1, f2o = c2;

    auto fetch = [&](int sl) {
        ub[sl]  = *(const u16*)(h2b + fu);
        dlr[sl] = *(const uint2*)(dlb_ + f1);
        B4[sl]  = *(const uint4*)(bcb_ + f2o);
        C4[sl]  = *(const uint4*)(bcb_ + f2o + 16);
        fu += (u32)su; f1 += (u32)s1; f2o += (u32)s2;
    };

    #pragma unroll
    for (int i = 0; i < 4; ++i) fetch(i);

    f2 h0 = {0.f,0.f}, h1v = {0.f,0.f}, h2v = {0.f,0.f}, h3 = {0.f,0.f};

    if (fast) {
        f2 a01, a23, a45, a67;
        f2 Bq0, Bq1, Bq2, Bq3;
        f2 Cp0, Cp1, Cp2, Cp3;
        float ydc;

        auto prep = [&](int sl) {
            float uu = bf2f(ub[sl]);
            uint2 dl = dlr[sl];
            uint4 Bv = B4[sl], Cv = C4[sl];
            float z = dbc + dw0*bflo(dl.x) + dw1*bfhi(dl.x)
                          + dw2*bflo(dl.y) + dw3*bfhi(dl.y);
            z = fminf(z, 80.f);
            float ez = __expf(z);
            float w  = 1.f + ez;
            float rr = __builtin_amdgcn_rcpf(w);   // = exp(-dt)
            float dt = __logf(w);                  // softplus(z); parallel with rcp
            float r2 = rr*rr;
            f2 rr2 = {r2, r2};
            f2 t01 = {rr, r2};
            a01 = t01;
            a23 = t01*rr2;
            a45 = a23*rr2;
            a67 = a45*rr2;
            float dtu = dt*uu;
            f2 du2 = {dtu, dtu};
            f2 Bp0 = { bflo(Bv.x), bfhi(Bv.x) }, Bp1 = { bflo(Bv.y), bfhi(Bv.y) };
            f2 Bp2 = { bflo(Bv.z), bfhi(Bv.z) }, Bp3 = { bflo(Bv.w), bfhi(Bv.w) };
            Bq0 = du2*Bp0; Bq1 = du2*Bp1; Bq2 = du2*Bp2; Bq3 = du2*Bp3;
            f2 c0 = { bflo(Cv.x), bfhi(Cv.x) }, c1v = { bflo(Cv.y), bfhi(Cv.y) };
            f2 c2v = { bflo(Cv.z), bfhi(Cv.z) }, c3 = { bflo(Cv.w), bfhi(Cv.w) };
            Cp0 = c0; Cp1 = c1v; Cp2 = c2v; Cp3 = c3;
            ydc = Dd*uu;
        };

        prep(0);

        #pragma unroll 4
        for (int t = 0; t < 384; ++t) {
            int sl = t & 3;
            fetch(sl);

            h0  = __builtin_elementwise_fma(a01, h0,  Bq0);
            h1v = __builtin_elementwise_fma(a23, h1v, Bq1);
            h2v = __builtin_elementwise_fma(a45, h2v, Bq2);
            h3  = __builtin_elementwise_fma(a67, h3,  Bq3);

            f2 yv = Cp0*h0;
            yv = __builtin_elementwise_fma(Cp1, h1v, yv);
            yv = __builtin_elementwise_fma(Cp2, h2v, yv);
            yv = __builtin_elementwise_fma(Cp3, h3,  yv);
            float y = yv.x + yv.y + ydc;

            prep((t+1) & 3);

            *(u16*)(y4b + yo) = f2bf(y);
            yo += (u32)sy;
        }
    } else {
        f2 A2[4];
        #pragma unroll
        for (int j = 0; j < 4; ++j) { A2[j].x = Av[2*j]; A2[j].y = Av[2*j+1]; }
        #pragma unroll 4
        for (int t = 0; t < 384; ++t) {
            int sl = t & 3;
            float uu = bf2f(ub[sl]);
            uint2 dl = dlr[sl];
            uint4 Bv = B4[sl], Cv = C4[sl];
            fetch(sl);

            float z = dbc + dw0*bflo(dl.x) + dw1*bfhi(dl.x)
                          + dw2*bflo(dl.y) + dw3*bfhi(dl.y);
            float dt = softplus_f(z);
            f2 dt2 = {dt, dt};
            f2 e0 = dt2*A2[0], e1 = dt2*A2[1], e2 = dt2*A2[2], e3 = dt2*A2[3];
            f2 a01 = { __expf(e0.x), __expf(e0.y) };
            f2 a23 = { __expf(e1.x), __expf(e1.y) };
            f2 a45 = { __expf(e2.x), __expf(e2.y) };
            f2 a67 = { __expf(e3.x), __expf(e3.y) };

            float dtu = dt*uu;
            f2 du2 = {dtu, dtu};
            f2 Bp0 = { bflo(Bv.x), bfhi(Bv.x) }, Bp1 = { bflo(Bv.y), bfhi(Bv.y) };
            f2 Bp2 = { bflo(Bv.z), bfhi(Bv.z) }, Bp3 = { bflo(Bv.w), bfhi(Bv.w) };
            f2 Cp0 = { bflo(Cv.x), bfhi(Cv.x) }, Cp1 = { bflo(Cv.y), bfhi(Cv.y) };
            f2 Cp2 = { bflo(Cv.z), bfhi(Cv.z) }, Cp3 = { bflo(Cv.w), bfhi(Cv.w) };

            h0  = __builtin_elementwise_fma(a01, h0,  du2*Bp0);
            h1v = __builtin_elementwise_fma(a23, h1v, du2*Bp1);
            h2v = __builtin_elementwise_fma(a45, h2v, du2*Bp2);
            h3  = __builtin_elementwise_fma(a67, h3,  du2*Bp3);

            f2 yv = Cp0*h0;
            yv = __builtin_elementwise_fma(Cp1, h1v, yv);
            yv = __builtin_elementwise_fma(Cp2, h2v, yv);
            yv = __builtin_elementwise_fma(Cp3, h3,  yv);

            float y = yv.x + yv.y + Dd*uu;
            *(u16*)(y4b + yo) = f2bf(y);
            yo += (u32)sy;
        }
    }
}

// ---------------- K5: LN(128) + folded 128->20 + transpose, 2-pixel blocking [R14 proven] ----------------
__global__ __launch_bounds__(256) void k_merge(
    const u16* __restrict__ y4, const float* __restrict__ Wt,
    const float* __restrict__ rsum, const float* __restrict__ c0,
    float* __restrict__ out)
{
    __shared__ __align__(16) f2 Wt2_s[128*10];   // [k][o2] = {Wt[k][2o2], Wt[k][2o2+1]}
    __shared__ float rs_s[CIN], c0_s[CIN];
    for (int i = threadIdx.x; i < 128*10; i += 256) {
        int k = i / 10, o2 = i % 10;
        Wt2_s[i] = f2{ Wt[k*CIN + 2*o2], Wt[k*CIN + 2*o2 + 1] };
    }
    if (threadIdx.x < CIN) { rs_s[threadIdx.x] = rsum[threadIdx.x]; c0_s[threadIdx.x] = c0[threadIdx.x]; }
    __syncthreads();

    int p = (blockIdx.x*256 + threadIdx.x)*2;
    int b = p / HW, rem = p % HW;    // p even, HW even: pair never straddles b

    float s1a = 0.f, s2a = 0.f, s1b = 0.f, s2b = 0.f;
    f2 acca[10], accb[10];
    #pragma unroll
    for (int o2 = 0; o2 < 10; ++o2) { acca[o2] = f2{0.f,0.f}; accb[o2] = f2{0.f,0.f}; }

    #pragma unroll 1
    for (int dirk = 0; dirk < 4; ++dirk) {
        const uint4* src = (const uint4*)(y4 + ((size_t)dirk*BHW + p)*32);
        #pragma unroll
        for (int q4 = 0; q4 < 4; ++q4) {
            uint4 va = src[q4];
            uint4 vb = src[q4+4];
            u32 wa[4] = {va.x, va.y, va.z, va.w};
            u32 wb[4] = {vb.x, vb.y, vb.z, vb.w};
            #pragma unroll
            for (int i = 0; i < 4; ++i) {
                int k = dirk*32 + q4*8 + i*2;
                float aa = bflo(wa[i]); float ca = bfhi(wa[i]);
                float ab = bflo(wb[i]); float cb = bfhi(wb[i]);
                s1a += aa + ca; s2a += aa*aa + ca*ca;
                s1b += ab + cb; s2b += ab*ab + cb*cb;
                f2 afa = {aa, aa}, cfa = {ca, ca};
                f2 afb = {ab, ab}, cfb = {cb, cb};
                const float4* w0 = (const float4*)&Wt2_s[k*10];
                const float4* w1 = (const float4*)&Wt2_s[(k+1)*10];
                #pragma unroll
                for (int jq = 0; jq < 5; ++jq) {
                    float4 x0 = w0[jq], x1 = w1[jq];
                    f2 x0lo = {x0.x, x0.y}, x0hi = {x0.z, x0.w};
                    f2 x1lo = {x1.x, x1.y}, x1hi = {x1.z, x1.w};
                    acca[2*jq]   = __builtin_elementwise_fma(x0lo, afa, acca[2*jq]);
                    acca[2*jq]   = __builtin_elementwise_fma(x1lo, cfa, acca[2*jq]);
                    acca[2*jq+1] = __builtin_elementwise_fma(x0hi, afa, acca[2*jq+1]);
                    acca[2*jq+1] = __builtin_elementwise_fma(x1hi, cfa, acca[2*jq+1]);
                    accb[2*jq]   = __builtin_elementwise_fma(x0lo, afb, accb[2*jq]);
                    accb[2*jq]   = __builtin_elementwise_fma(x1lo, cfb, accb[2*jq]);
                    accb[2*jq+1] = __builtin_elementwise_fma(x0hi, afb, accb[2*jq+1]);
                    accb[2*jq+1] = __builtin_elementwise_fma(x1hi, cfb, accb[2*jq+1]);
                }
            }
        }
    }
    float ma = s1a*(1.f/128.f);
    float va = s2a*(1.f/128.f) - ma*ma;
    float ra = rsqrtf(va + EPSF);
    float mb2 = s1b*(1.f/128.f);
    float vb2 = s2b*(1.f/128.f) - mb2*mb2;
    float rb = rsqrtf(vb2 + EPSF);
    #pragma unroll
    for (int o2 = 0; o2 < 10; ++o2) {
        float a0 = ra*(acca[o2].x - ma*rs_s[2*o2])    + c0_s[2*o2];
        float a1 = ra*(acca[o2].y - ma*rs_s[2*o2+1])  + c0_s[2*o2+1];
        float b0 = rb*(accb[o2].x - mb2*rs_s[2*o2])   + c0_s[2*o2];
        float b1 = rb*(accb[o2].y - mb2*rs_s[2*o2+1]) + c0_s[2*o2+1];
        *(float2*)&out[(b*CIN + 2*o2)*HW + rem]   = float2{a0, b0};
        *(float2*)&out[(b*CIN + 2*o2+1)*HW + rem] = float2{a1, b1};
    }
}

extern "C" void kernel_launch(void* const* d_in, const int* in_sizes, int n_in,
                              void* d_out, int out_size, void* d_ws, size_t ws_size,
                              hipStream_t stream)
{
    const float* x    = (const float*)d_in[0];
    const float* ng   = (const float*)d_in[1];
    const float* nb   = (const float*)d_in[2];
    const float* ipw  = (const float*)d_in[3];
    const float* cw   = (const float*)d_in[4];
    const float* cb   = (const float*)d_in[5];
    const float* xw   = (const float*)d_in[6];
    const float* dwm  = (const float*)d_in[7];
    const float* dbv  = (const float*)d_in[8];
    const float* Alog = (const float*)d_in[9];
    const float* Dpv  = (const float*)d_in[10];
    const float* mg   = (const float*)d_in[11];
    const float* mb   = (const float*)d_in[12];
    const float* mw   = (const float*)d_in[13];
    const float* ow   = (const float*)d_in[14];
    const float* ob   = (const float*)d_in[15];
    float* out = (float*)d_out;

    const size_t y4_bytes = (size_t)4*BHW*DIN*2;     // 150,994,944 (planar)
    const size_t dl_bytes = (size_t)4*BHW*8;         //  18,874,368
    const size_t bc_bytes = (size_t)4*BHW*32;        //  75,497,472
    const size_t wt_bytes = (size_t)(128*CIN + 64)*4;

    char* ws = (char*)d_ws;
    u16* y4 = (u16*)ws;

    size_t dl_pos = y4_bytes + GUARD;
    size_t bc_pos = dl_pos + dl_bytes + GUARD;
    size_t wt_pos = bc_pos + bc_bytes + GUARD;
    size_t need   = wt_pos + wt_bytes + GUARD;       // ~245.6 MB (proven budget; ws < 321MB per R4)

    if (ws_size < need) {
        hipMemsetAsync(d_out, 0x7F, (size_t)out_size*4, stream);  // diagnosable sentinel
        return;
    }

    // h2 (u after conv) lives inside d_out with UGUARD front guard (128K for
    // 4-deep prefetch overrun of the vertical-scan u stream: 4*24576 = 96K).
    char* h2base = (char*)d_out;                     // data at +UGUARD
    u16*  h2 = (u16*)(h2base + UGUARD);              // 128K + 37.75MB + 9.3MB tail < 47.19 MB

    u16* dlA = (u16*)(ws + dl_pos);
    u16* bcA = (u16*)(ws + bc_pos);
    float* Wt   = (float*)(ws + wt_pos);
    float* rsum = Wt + 128*CIN;
    float* c0   = rsum + 32;

    k_front <<<2304, 256, 0, stream>>>(x, ng, nb, ipw, cw, cb, xw,
                                       ow, mw, mg, mb, ob,
                                       h2, dlA, bcA, Wt, rsum, c0);
    k_scan  <<<768, 256, 0, stream>>>(
        h2base, (const char*)(ws + dl_pos - GUARD), (const char*)(ws + bc_pos - GUARD),
        Alog, Dpv, dwm, dbv, (char*)y4);
    k_merge <<<BHW/512, 256, 0, stream>>>(y4, Wt, rsum, c0, out);
}